// Round 6
// baseline (378.145 us; speedup 1.0000x reference)
//
#include <hip/hip_runtime.h>
#include <hip/hip_cooperative_groups.h>

namespace cg = cooperative_groups;

// DirectionalConv3d: B=8, C_IN=C_OUT=64, T=R=32, CO=32
// v7 design: ONE cooperative kernel (discovered ~92us fixed harness overhead;
// objective = minimize sum of kernel times; prep pass was 27us of pure layout).
//  conv7 (cooperative, 1024 blocks x 256 thr, exactly 4 blocks/CU co-resident):
//   phase 1: each block converts its own 256-row slab fp32 [ch][s] -> bf16
//     [s][ch] into xq AND into its own 40KB xor-swizzled LDS center (no
//     restage). First 7 blocks also convert weights. grid.sync().
//   phase 2: DMA the 64 halo rows from neighbors' xq (L2-hot, XCD-pinned),
//     prefetch t+-1 A-frags to regs, then conv5's verified 7-tap MFMA compute.
//  Fallback chain: cooperative-launch error -> prep2+conv5 (proven 77us pair);
//  small ws -> tier-2 fused fp32 kernel; no ws -> tier-3 fp32 direct.

#define SB 32768   // spatial per batch (T*R*CO)
#define CIN 64
#define COUT 64
#define NB 8

typedef short s16x8 __attribute__((ext_vector_type(8)));
typedef __bf16 bf16x8 __attribute__((ext_vector_type(8)));
typedef float f32x4 __attribute__((ext_vector_type(4)));

__device__ __forceinline__ unsigned f2bf(float f) {
    unsigned u = __float_as_uint(f);
    u += 0x7FFFu + ((u >> 16) & 1u);   // round-to-nearest-even
    return u >> 16;
}
__device__ __forceinline__ unsigned pk2(float lo, float hi) {
    return f2bf(lo) | (f2bf(hi) << 16);
}

__device__ __forceinline__ void gload_lds16(const void* g, void* l) {
    __builtin_amdgcn_global_load_lds(
        (const __attribute__((address_space(1))) void*)g,
        (__attribute__((address_space(3))) void*)l, 16, 0, 0);
}

// ---------------- cooperative fused kernel ----------------
__global__ __launch_bounds__(256, 4) void conv7_kernel(const float* __restrict__ x,
        const float* __restrict__ w0, const float* __restrict__ w1,
        const float* __restrict__ w2, const float* __restrict__ w3,
        const float* __restrict__ w4, const float* __restrict__ w5,
        const float* __restrict__ w6,
        unsigned short* __restrict__ ws, float* __restrict__ out) {
    __shared__ uint4 alds[2560];   // 40 KB: local rows 0..319 (center 32..287 from phase1)
    int bid = blockIdx.x;
    int lbid = ((bid & 7) << 7) | (bid >> 3);   // bijective; batch b pinned to XCD b
    int b = lbid >> 7;
    int sblk = (lbid & 127) << 8;
    int tid = threadIdx.x;
    unsigned short* wq = ws;
    unsigned short* xq = ws + 7 * 4096;
    const float* xb32 = x + (size_t)b * CIN * SB;
    uint4* xcw = (uint4*)(xq + (size_t)b * (CIN * SB));   // bf16 [s][ch] chunks

    // ================= phase 1: convert own slab =================
    // item = (s2, cg): 2 rows x 8 ch. 1024 items/block, 4/thread.
    // Reads: 8 x float2 along s per item (64B segments across lanes).
    // Writes: 2 x uint4 to xq (contig) + 2 swizzled LDS writes (center rows).
#pragma unroll
    for (int it = 0; it < 4; ++it) {
        int item = it * 256 + tid;
        int cgp = item & 7;
        int s = sblk + (item >> 3) * 2;
        unsigned pa[4], pb[4];
#pragma unroll
        for (int u = 0; u < 4; ++u) {
            int ch = cgp * 8 + 2 * u;
            float2 v0 = *(const float2*)(xb32 + (size_t)ch * SB + s);
            float2 v1 = *(const float2*)(xb32 + (size_t)(ch + 1) * SB + s);
            pa[u] = pk2(v0.x, v1.x);
            pb[u] = pk2(v0.y, v1.y);
        }
        uint4 va = make_uint4(pa[0], pa[1], pa[2], pa[3]);
        uint4 vb = make_uint4(pb[0], pb[1], pb[2], pb[3]);
        xcw[(size_t)s * 8 + cgp] = va;
        xcw[(size_t)(s + 1) * 8 + cgp] = vb;
        int lr = s - sblk + 32;                       // 32..286, even
        alds[lr * 8 + (cgp ^ (lr & 7))] = va;
        alds[(lr + 1) * 8 + (cgp ^ ((lr + 1) & 7))] = vb;
    }
    // first 7 blocks also convert weights -> wq [tap][o][i]
    if (bid < 7) {
        const float* w = (bid == 0) ? w0 : (bid == 1) ? w1 : (bid == 2) ? w2
                       : (bid == 3) ? w3 : (bid == 4) ? w4 : (bid == 5) ? w5 : w6;
        unsigned p[8];
#pragma unroll
        for (int j = 0; j < 8; ++j)
            p[j] = pk2(w[tid * 16 + 2 * j], w[tid * 16 + 2 * j + 1]);
        uint4* dp = (uint4*)(wq + bid * 4096 + tid * 16);
        dp[0] = make_uint4(p[0], p[1], p[2], p[3]);
        dp[1] = make_uint4(p[4], p[5], p[6], p[7]);
    }

    cg::this_grid().sync();   // all xq slabs + weights visible device-wide

    // ================= phase 2: halo DMA + t-prefetch + 7-tap MFMA =================
    int lane = tid & 63;
    int wv = tid >> 6;
    int lo = lane & 15;
    int quad = lane >> 4;
    int sbase = sblk + wv * 64;
    int t = sblk >> 10;                               // block-uniform
    const uint4* xch = (const uint4*)(xq + (size_t)b * (CIN * SB));

    // halo rows: local 0..31 (low) and 288..319 (high); 512 chunks, 2 DMA/thread.
    // LDS dest linear in cid; source col pre-swizzled -> same layout as phase 1.
    {
        int cid = tid;                                 // u = 0: rows 0..31
        int row = cid >> 3;
        int sc = cid & 7;
        int grow = sblk - 32 + row;
        grow = grow < 0 ? 0 : grow;                    // clamped rows feed masked lanes only
        gload_lds16((const void*)(xch + ((size_t)grow << 3) + (sc ^ (row & 7))),
                    (void*)(alds + wv * 64));
    }
    {
        int cid = tid;                                 // u = 1: rows 288..319
        int row = (cid >> 3) + 288;
        int sc = cid & 7;
        int grow = sblk - 32 + row;
        grow = grow > SB - 1 ? SB - 1 : grow;
        gload_lds16((const void*)(xch + ((size_t)grow << 3) + (sc ^ (row & 7))),
                    (void*)(alds + 2304 + wv * 64));
    }

    int s_m[4], r_m[4], c_m[4], rl[4];
#pragma unroll
    for (int mt = 0; mt < 4; ++mt) {
        int s = sbase + mt * 16 + lo;                  // A row: m = lane&15
        s_m[mt] = s;
        r_m[mt] = (s >> 5) & 31;
        c_m[mt] = s & 31;
        rl[mt] = s - sblk + 32;
    }

    // t+-1 A-frag prefetch (block-uniform validity), drained by the barrier
    bool htm = (t > 0), htp = (t < 31);
    uint4 tgm[8], tgp[8];
    if (htm) {
#pragma unroll
        for (int ks = 0; ks < 2; ++ks)
#pragma unroll
            for (int mt = 0; mt < 4; ++mt)
                tgm[ks * 4 + mt] = xch[(size_t)(s_m[mt] - 1024) * 8 + ks * 4 + quad];
    }
    if (htp) {
#pragma unroll
        for (int ks = 0; ks < 2; ++ks)
#pragma unroll
            for (int mt = 0; mt < 4; ++mt)
                tgp[ks * 4 + mt] = xch[(size_t)(s_m[mt] + 1024) * 8 + ks * 4 + quad];
    }

    __syncthreads();   // drains vmcnt(0): halo DMA + prefetch complete

    f32x4 acc[4][4];
#pragma unroll
    for (int mt = 0; mt < 4; ++mt)
#pragma unroll
        for (int nt = 0; nt < 4; ++nt)
            acc[mt][nt] = (f32x4){0.f, 0.f, 0.f, 0.f};

    const s16x8 zz = {0, 0, 0, 0, 0, 0, 0, 0};

    auto load_b = [&](const unsigned short* wt, int ks, int nt) -> bf16x8 {
        const unsigned short* bp = wt + (nt * 16 + lo) * 64 + ks * 32 + quad * 8;
        return __builtin_bit_cast(bf16x8, *(const s16x8*)bp);
    };

    auto run_tap_reg = [&](int tap, const uint4 (&tg)[8]) {
        const unsigned short* wt = wq + tap * 4096;
        bf16x8 bf[2][4];
#pragma unroll
        for (int ks = 0; ks < 2; ++ks)
#pragma unroll
            for (int nt = 0; nt < 4; ++nt) bf[ks][nt] = load_b(wt, ks, nt);
#pragma unroll
        for (int ks = 0; ks < 2; ++ks)
#pragma unroll
            for (int mt = 0; mt < 4; ++mt) {
                bf16x8 af = __builtin_bit_cast(bf16x8, tg[ks * 4 + mt]);
#pragma unroll
                for (int nt = 0; nt < 4; ++nt)
                    acc[mt][nt] = __builtin_amdgcn_mfma_f32_16x16x32_bf16(af, bf[ks][nt], acc[mt][nt], 0, 0, 0);
            }
    };

    auto run_tap_lds = [&](int tap, int d, const bool (&ok)[4]) {
        const unsigned short* wt = wq + tap * 4096;
        bf16x8 bf[2][4];
#pragma unroll
        for (int ks = 0; ks < 2; ++ks)
#pragma unroll
            for (int nt = 0; nt < 4; ++nt) bf[ks][nt] = load_b(wt, ks, nt);
        s16x8 a[2][4];
#pragma unroll
        for (int ks = 0; ks < 2; ++ks)
#pragma unroll
            for (int mt = 0; mt < 4; ++mt) {
                int row = rl[mt] + d;                  // always in [0,320)
                a[ks][mt] = *((const s16x8*)alds + row * 8 + ((ks * 4 + quad) ^ (row & 7)));
            }
#pragma unroll
        for (int ks = 0; ks < 2; ++ks)
#pragma unroll
            for (int mt = 0; mt < 4; ++mt) {
                s16x8 raw = ok[mt] ? a[ks][mt] : zz;
                bf16x8 af = __builtin_bit_cast(bf16x8, raw);
#pragma unroll
                for (int nt = 0; nt < 4; ++nt)
                    acc[mt][nt] = __builtin_amdgcn_mfma_f32_16x16x32_bf16(af, bf[ks][nt], acc[mt][nt], 0, 0, 0);
            }
    };

    if (htm) run_tap_reg(1, tgm);                      // t-1
    if (htp) run_tap_reg(2, tgp);                      // t+1
    {
        bool ok_all[4] = {true, true, true, true};
        run_tap_lds(0, 0, ok_all);                     // self
    }
    {
        bool ok[4];
#pragma unroll
        for (int mt = 0; mt < 4; ++mt) ok[mt] = (r_m[mt] > 0);
        run_tap_lds(3, -32, ok);                       // r-1
#pragma unroll
        for (int mt = 0; mt < 4; ++mt) ok[mt] = (r_m[mt] < 31);
        run_tap_lds(4, 32, ok);                        // r+1
#pragma unroll
        for (int mt = 0; mt < 4; ++mt) ok[mt] = (c_m[mt] > 0);
        run_tap_lds(5, -1, ok);                        // c-1
#pragma unroll
        for (int mt = 0; mt < 4; ++mt) ok[mt] = (c_m[mt] < 31);
        run_tap_lds(6, 1, ok);                         // c+1
    }

    // D layout: col(n=o) = lane&15, row(m=s) = quad*4 + reg -> full 64B lines per wave
#pragma unroll
    for (int mt = 0; mt < 4; ++mt) {
#pragma unroll
        for (int nt = 0; nt < 4; ++nt) {
            int o = nt * 16 + lo;
            size_t off = ((size_t)(b * COUT + o)) * SB + sbase + mt * 16 + quad * 4;
            *(f32x4*)(out + off) = acc[mt][nt];
        }
    }
}

// ---------------- fallback pass 1: weights + x transpose/convert ----------------
__global__ __launch_bounds__(256) void prep2_kernel(const float* __restrict__ x,
                            const float* __restrict__ w0, const float* __restrict__ w1,
                            const float* __restrict__ w2, const float* __restrict__ w3,
                            const float* __restrict__ w4, const float* __restrict__ w5,
                            const float* __restrict__ w6,
                            unsigned short* __restrict__ ws) {
    int bid = blockIdx.x;
    int tid = threadIdx.x;
    if (bid >= 4096) {                 // weight blocks
        int tap = bid - 4096;
        const float* w = (tap == 0) ? w0 : (tap == 1) ? w1 : (tap == 2) ? w2
                       : (tap == 3) ? w3 : (tap == 4) ? w4 : (tap == 5) ? w5 : w6;
        unsigned p[8];
#pragma unroll
        for (int j = 0; j < 8; ++j)
            p[j] = pk2(w[tid * 16 + 2 * j], w[tid * 16 + 2 * j + 1]);
        uint4* dp = (uint4*)(ws + tap * 4096 + tid * 16);
        dp[0] = make_uint4(p[0], p[1], p[2], p[3]);
        dp[1] = make_uint4(p[4], p[5], p[6], p[7]);
        return;
    }
    int lbid = ((bid & 7) << 9) | (bid >> 3);   // bijective: 4096 % 8 == 0
    int b = lbid >> 9;                          // batch = XCD
    int i = (lbid & 511) * 256 + tid;
    int cgp = i & 7;
    int s = (i >> 3) * 2;
    const float* xb = x + (size_t)b * CIN * SB;
    unsigned short* xq = ws + 7 * 4096;
    unsigned pa[4], pb[4];
#pragma unroll
    for (int u = 0; u < 4; ++u) {
        int ch = cgp * 8 + 2 * u;
        float2 v0 = *(const float2*)(xb + (size_t)ch * SB + s);
        float2 v1 = *(const float2*)(xb + (size_t)(ch + 1) * SB + s);
        pa[u] = pk2(v0.x, v1.x);
        pb[u] = pk2(v0.y, v1.y);
    }
    uint4* dst = (uint4*)(xq + ((size_t)b * SB + s) * 64 + cgp * 8);
    dst[0] = make_uint4(pa[0], pa[1], pa[2], pa[3]);
    dst[8] = make_uint4(pb[0], pb[1], pb[2], pb[3]);
}

// ---------------- fallback pass 2: async-staged MFMA conv (proven 50us) ----------------
__global__ __launch_bounds__(256, 2) void conv5_kernel(const unsigned short* __restrict__ xq,
                                                       const unsigned short* __restrict__ wq,
                                                       float* __restrict__ out) {
    __shared__ uint4 alds[2560];
    int bid = blockIdx.x;
    int lbid = ((bid & 7) << 7) | (bid >> 3);
    int b = lbid >> 7;
    int sblk = (lbid & 127) << 8;
    int tid = threadIdx.x;
    int lane = tid & 63;
    int wv = tid >> 6;
    int lo = lane & 15;
    int quad = lane >> 4;
    int sbase = sblk + wv * 64;
    int t = sblk >> 10;
    const uint4* xch = (const uint4*)(xq + (size_t)b * (CIN * SB));

#pragma unroll
    for (int i = 0; i < 10; ++i) {
        int cid = wv * 640 + i * 64 + lane;
        int row = cid >> 3;
        int sc = cid & 7;
        int grow = sblk - 32 + row;
        grow = grow < 0 ? 0 : (grow > SB - 1 ? SB - 1 : grow);
        const uint4* g = xch + ((size_t)grow << 3) + (sc ^ (row & 7));
        gload_lds16((const void*)g, (void*)(alds + wv * 640 + i * 64));
    }

    int s_m[4], r_m[4], c_m[4], rl[4];
#pragma unroll
    for (int mt = 0; mt < 4; ++mt) {
        int s = sbase + mt * 16 + lo;
        s_m[mt] = s;
        r_m[mt] = (s >> 5) & 31;
        c_m[mt] = s & 31;
        rl[mt] = s - sblk + 32;
    }

    bool htm = (t > 0), htp = (t < 31);
    uint4 tgm[8], tgp[8];
    if (htm) {
#pragma unroll
        for (int ks = 0; ks < 2; ++ks)
#pragma unroll
            for (int mt = 0; mt < 4; ++mt)
                tgm[ks * 4 + mt] = xch[(size_t)(s_m[mt] - 1024) * 8 + ks * 4 + quad];
    }
    if (htp) {
#pragma unroll
        for (int ks = 0; ks < 2; ++ks)
#pragma unroll
            for (int mt = 0; mt < 4; ++mt)
                tgp[ks * 4 + mt] = xch[(size_t)(s_m[mt] + 1024) * 8 + ks * 4 + quad];
    }

    __syncthreads();

    f32x4 acc[4][4];
#pragma unroll
    for (int mt = 0; mt < 4; ++mt)
#pragma unroll
        for (int nt = 0; nt < 4; ++nt)
            acc[mt][nt] = (f32x4){0.f, 0.f, 0.f, 0.f};

    const s16x8 zz = {0, 0, 0, 0, 0, 0, 0, 0};

    auto load_b = [&](const unsigned short* wt, int ks, int nt) -> bf16x8 {
        const unsigned short* bp = wt + (nt * 16 + lo) * 64 + ks * 32 + quad * 8;
        return __builtin_bit_cast(bf16x8, *(const s16x8*)bp);
    };

    auto run_tap_reg = [&](int tap, const uint4 (&tg)[8]) {
        const unsigned short* wt = wq + tap * 4096;
        bf16x8 bf[2][4];
#pragma unroll
        for (int ks = 0; ks < 2; ++ks)
#pragma unroll
            for (int nt = 0; nt < 4; ++nt) bf[ks][nt] = load_b(wt, ks, nt);
#pragma unroll
        for (int ks = 0; ks < 2; ++ks)
#pragma unroll
            for (int mt = 0; mt < 4; ++mt) {
                bf16x8 af = __builtin_bit_cast(bf16x8, tg[ks * 4 + mt]);
#pragma unroll
                for (int nt = 0; nt < 4; ++nt)
                    acc[mt][nt] = __builtin_amdgcn_mfma_f32_16x16x32_bf16(af, bf[ks][nt], acc[mt][nt], 0, 0, 0);
            }
    };

    auto run_tap_lds = [&](int tap, int d, const bool (&ok)[4]) {
        const unsigned short* wt = wq + tap * 4096;
        bf16x8 bf[2][4];
#pragma unroll
        for (int ks = 0; ks < 2; ++ks)
#pragma unroll
            for (int nt = 0; nt < 4; ++nt) bf[ks][nt] = load_b(wt, ks, nt);
        s16x8 a[2][4];
#pragma unroll
        for (int ks = 0; ks < 2; ++ks)
#pragma unroll
            for (int mt = 0; mt < 4; ++mt) {
                int row = rl[mt] + d;
                a[ks][mt] = *((const s16x8*)alds + row * 8 + ((ks * 4 + quad) ^ (row & 7)));
            }
#pragma unroll
        for (int ks = 0; ks < 2; ++ks)
#pragma unroll
            for (int mt = 0; mt < 4; ++mt) {
                s16x8 raw = ok[mt] ? a[ks][mt] : zz;
                bf16x8 af = __builtin_bit_cast(bf16x8, raw);
#pragma unroll
                for (int nt = 0; nt < 4; ++nt)
                    acc[mt][nt] = __builtin_amdgcn_mfma_f32_16x16x32_bf16(af, bf[ks][nt], acc[mt][nt], 0, 0, 0);
            }
    };

    if (htm) run_tap_reg(1, tgm);
    if (htp) run_tap_reg(2, tgp);
    {
        bool ok_all[4] = {true, true, true, true};
        run_tap_lds(0, 0, ok_all);
    }
    {
        bool ok[4];
#pragma unroll
        for (int mt = 0; mt < 4; ++mt) ok[mt] = (r_m[mt] > 0);
        run_tap_lds(3, -32, ok);
#pragma unroll
        for (int mt = 0; mt < 4; ++mt) ok[mt] = (r_m[mt] < 31);
        run_tap_lds(4, 32, ok);
#pragma unroll
        for (int mt = 0; mt < 4; ++mt) ok[mt] = (c_m[mt] > 0);
        run_tap_lds(5, -1, ok);
#pragma unroll
        for (int mt = 0; mt < 4; ++mt) ok[mt] = (c_m[mt] < 31);
        run_tap_lds(6, 1, ok);
    }

#pragma unroll
    for (int mt = 0; mt < 4; ++mt) {
#pragma unroll
        for (int nt = 0; nt < 4; ++nt) {
            int o = nt * 16 + lo;
            size_t off = ((size_t)(b * COUT + o)) * SB + sbase + mt * 16 + quad * 4;
            *(f32x4*)(out + off) = acc[mt][nt];
        }
    }
}

// ---------------- tier-2 fallback: weights only ----------------
__global__ __launch_bounds__(256) void wprep_kernel(const float* __restrict__ w0,
                            const float* __restrict__ w1, const float* __restrict__ w2,
                            const float* __restrict__ w3, const float* __restrict__ w4,
                            const float* __restrict__ w5, const float* __restrict__ w6,
                            unsigned short* __restrict__ ws) {
    int tap = blockIdx.x;
    int tid = threadIdx.x;
    const float* w = (tap == 0) ? w0 : (tap == 1) ? w1 : (tap == 2) ? w2
                   : (tap == 3) ? w3 : (tap == 4) ? w4 : (tap == 5) ? w5 : w6;
    unsigned p[8];
#pragma unroll
    for (int j = 0; j < 8; ++j)
        p[j] = pk2(w[tid * 16 + 2 * j], w[tid * 16 + 2 * j + 1]);
    uint4* dp = (uint4*)(ws + tap * 4096 + tid * 16);
    dp[0] = make_uint4(p[0], p[1], p[2], p[3]);
    dp[1] = make_uint4(p[4], p[5], p[6], p[7]);
}

// ---------------- tier-2 fallback: fused LDS kernel on fp32 x ----------------
__global__ __launch_bounds__(256) void conv_kernel(const float* __restrict__ x,
                                                   const unsigned short* __restrict__ wq,
                                                   float* __restrict__ out) {
    __shared__ uint4 alds[2560];
    int bid = blockIdx.x;
    int b = bid >> 7;
    int sblk = (bid & 127) << 8;
    int tid = threadIdx.x;
    const float* xb = x + (size_t)b * CIN * SB;

    {
        int rl = 32 + tid;
        const float* xp = xb + sblk + tid;
#pragma unroll
        for (int c = 0; c < 4; ++c) {
            unsigned pk[8];
#pragma unroll
            for (int u = 0; u < 8; ++u)
                pk[u] = pk2(xp[(size_t)(c * 16 + 2 * u) * SB],
                            xp[(size_t)(c * 16 + 2 * u + 1) * SB]);
            alds[rl * 8 + ((2 * c) ^ (rl & 7))] = make_uint4(pk[0], pk[1], pk[2], pk[3]);
            alds[rl * 8 + ((2 * c + 1) ^ (rl & 7))] = make_uint4(pk[4], pk[5], pk[6], pk[7]);
        }
    }
    {
        int hrow = tid & 63;
        int rl = (hrow < 32) ? hrow : hrow + 256;
        int s = sblk - 32 + rl;
        s = max(0, min(SB - 1, s));
        int ic = tid >> 6;
        const float* xp = xb + s + (size_t)(ic * 16) * SB;
        unsigned pk[8];
#pragma unroll
        for (int u = 0; u < 8; ++u)
            pk[u] = pk2(xp[(size_t)(2 * u) * SB], xp[(size_t)(2 * u + 1) * SB]);
        alds[rl * 8 + ((2 * ic) ^ (rl & 7))] = make_uint4(pk[0], pk[1], pk[2], pk[3]);
        alds[rl * 8 + ((2 * ic + 1) ^ (rl & 7))] = make_uint4(pk[4], pk[5], pk[6], pk[7]);
    }
    __syncthreads();

    int lane = tid & 63;
    int wv = tid >> 6;
    int lo = lane & 15;
    int quad = lane >> 4;
    int sbase = sblk + wv * 64;
    int t = sblk >> 10;

    f32x4 acc[4][4];
#pragma unroll
    for (int mt = 0; mt < 4; ++mt)
#pragma unroll
        for (int nt = 0; nt < 4; ++nt)
            acc[mt][nt] = (f32x4){0.f, 0.f, 0.f, 0.f};

    int r_m[4], c_m[4], rl[4];
#pragma unroll
    for (int mt = 0; mt < 4; ++mt) {
        int s = sbase + mt * 16 + lo;
        r_m[mt] = (s >> 5) & 31;
        c_m[mt] = s & 31;
        rl[mt] = s - sblk + 32;
    }

    auto load_b = [&](const unsigned short* wt, int ks, int nt) -> bf16x8 {
        const unsigned short* bp = wt + (nt * 16 + lo) * 64 + ks * 32 + quad * 8;
        return __builtin_bit_cast(bf16x8, *(const s16x8*)bp);
    };

    auto run_tap_lds = [&](int tap, int d, const bool ok[4]) {
        const unsigned short* wt = wq + tap * 4096;
#pragma unroll
        for (int ks = 0; ks < 2; ++ks) {
            bf16x8 bf[4];
#pragma unroll
            for (int nt = 0; nt < 4; ++nt) bf[nt] = load_b(wt, ks, nt);
            int j = ks * 4 + quad;
#pragma unroll
            for (int mt = 0; mt < 4; ++mt) {
                int row = rl[mt] + d;
                s16x8 raw = *((const s16x8*)alds + row * 8 + (j ^ (row & 7)));
                s16x8 zx = {0, 0, 0, 0, 0, 0, 0, 0};
                raw = ok[mt] ? raw : zx;
                bf16x8 af = __builtin_bit_cast(bf16x8, raw);
#pragma unroll
                for (int nt = 0; nt < 4; ++nt)
                    acc[mt][nt] = __builtin_amdgcn_mfma_f32_16x16x32_bf16(af, bf[nt], acc[mt][nt], 0, 0, 0);
            }
        }
    };

    auto run_tap_gather = [&](int tap, int d) {
        const unsigned short* wt = wq + tap * 4096;
#pragma unroll
        for (int ks = 0; ks < 2; ++ks) {
            bf16x8 bf[4];
#pragma unroll
            for (int nt = 0; nt < 4; ++nt) bf[nt] = load_b(wt, ks, nt);
            const float* gp = xb + (size_t)(ks * 32 + quad * 8) * SB + d;
#pragma unroll
            for (int mt = 0; mt < 4; ++mt) {
                const float* ap = gp + sbase + mt * 16 + lo;
                unsigned pk[4];
#pragma unroll
                for (int u = 0; u < 4; ++u)
                    pk[u] = pk2(ap[(size_t)(2 * u) * SB], ap[(size_t)(2 * u + 1) * SB]);
                uint4 v = make_uint4(pk[0], pk[1], pk[2], pk[3]);
                bf16x8 af = __builtin_bit_cast(bf16x8, v);
#pragma unroll
                for (int nt = 0; nt < 4; ++nt)
                    acc[mt][nt] = __builtin_amdgcn_mfma_f32_16x16x32_bf16(af, bf[nt], acc[mt][nt], 0, 0, 0);
            }
        }
    };

    {
        bool ok_all[4] = {true, true, true, true};
        run_tap_lds(0, 0, ok_all);
    }
    if (t > 0)  run_tap_gather(1, -1024);
    if (t < 31) run_tap_gather(2, 1024);
    {
        bool ok[4];
#pragma unroll
        for (int mt = 0; mt < 4; ++mt) ok[mt] = (r_m[mt] > 0);
        run_tap_lds(3, -32, ok);
#pragma unroll
        for (int mt = 0; mt < 4; ++mt) ok[mt] = (r_m[mt] < 31);
        run_tap_lds(4, 32, ok);
#pragma unroll
        for (int mt = 0; mt < 4; ++mt) ok[mt] = (c_m[mt] > 0);
        run_tap_lds(5, -1, ok);
#pragma unroll
        for (int mt = 0; mt < 4; ++mt) ok[mt] = (c_m[mt] < 31);
        run_tap_lds(6, 1, ok);
    }

#pragma unroll
    for (int mt = 0; mt < 4; ++mt) {
#pragma unroll
        for (int nt = 0; nt < 4; ++nt) {
            int o = nt * 16 + lo;
            size_t off = ((size_t)(b * COUT + o)) * SB + sbase + mt * 16 + quad * 4;
            *(f32x4*)(out + off) = acc[mt][nt];
        }
    }
}

// ---------------- tier-3 fallback: fp32 direct ----------------
__global__ void fallback_kernel(const float* __restrict__ x,
                                const float* __restrict__ w0, const float* __restrict__ w1,
                                const float* __restrict__ w2, const float* __restrict__ w3,
                                const float* __restrict__ w4, const float* __restrict__ w5,
                                const float* __restrict__ w6,
                                float* __restrict__ out) {
    int bid = blockIdx.x;
    int b = bid >> 11;
    int og = (bid >> 7) & 15;
    int sblk = (bid & 127) << 8;
    int tid = threadIdx.x;
    __shared__ float wl[7][4][64];
    const float* wp[7] = {w0, w1, w2, w3, w4, w5, w6};
    for (int k = tid; k < 7 * 4 * 64; k += 256) {
        int tap = k >> 8, oo = (k >> 6) & 3, i = k & 63;
        wl[tap][oo][i] = wp[tap][(og * 4 + oo) * 64 + i];
    }
    __syncthreads();
    int s = sblk + tid;
    int t = s >> 10, r = (s >> 5) & 31, c = s & 31;
    const float* xb = x + (size_t)b * CIN * SB + s;
    float a0 = 0, a1 = 0, a2 = 0, a3 = 0;
    for (int i = 0; i < 64; ++i) {
        const float* xi = xb + (size_t)i * SB;
        float vs = xi[0];
        float vtp = (t > 0) ? xi[-1024] : 0.f;
        float vtm = (t < 31) ? xi[1024] : 0.f;
        float vrp = (r > 0) ? xi[-32] : 0.f;
        float vrm = (r < 31) ? xi[32] : 0.f;
        float vcp = (c > 0) ? xi[-1] : 0.f;
        float vcm = (c < 31) ? xi[1] : 0.f;
        a0 += wl[0][0][i] * vs + wl[1][0][i] * vtp + wl[2][0][i] * vtm + wl[3][0][i] * vrp + wl[4][0][i] * vrm + wl[5][0][i] * vcp + wl[6][0][i] * vcm;
        a1 += wl[0][1][i] * vs + wl[1][1][i] * vtp + wl[2][1][i] * vtm + wl[3][1][i] * vrp + wl[4][1][i] * vrm + wl[5][1][i] * vcp + wl[6][1][i] * vcm;
        a2 += wl[0][2][i] * vs + wl[1][2][i] * vtp + wl[2][2][i] * vtm + wl[3][2][i] * vrp + wl[4][2][i] * vrm + wl[5][2][i] * vcp + wl[6][2][i] * vcm;
        a3 += wl[0][3][i] * vs + wl[1][3][i] * vtp + wl[2][3][i] * vtm + wl[3][3][i] * vrp + wl[4][3][i] * vrm + wl[5][3][i] * vcp + wl[6][3][i] * vcm;
    }
    size_t obase = ((size_t)b * COUT + og * 4) * SB + s;
    out[obase] = a0;
    out[obase + SB] = a1;
    out[obase + 2 * (size_t)SB] = a2;
    out[obase + 3 * (size_t)SB] = a3;
}

extern "C" void kernel_launch(void* const* d_in, const int* in_sizes, int n_in,
                              void* d_out, int out_size, void* d_ws, size_t ws_size,
                              hipStream_t stream) {
    const float* x = (const float*)d_in[0];
    const float* w0 = (const float*)d_in[1];
    const float* w1 = (const float*)d_in[2];
    const float* w2 = (const float*)d_in[3];
    const float* w3 = (const float*)d_in[4];
    const float* w4 = (const float*)d_in[5];
    const float* w5 = (const float*)d_in[6];
    const float* w6 = (const float*)d_in[7];
    float* out = (float*)d_out;

    size_t need_w = (size_t)7 * 4096 * 2;                        // 56 KB weights
    size_t need_full = need_w + (size_t)NB * CIN * SB * 2;       // + 32 MB bf16 x
    if (d_ws != nullptr && ws_size >= need_full) {
        unsigned short* wsp = (unsigned short*)d_ws;
        void* kargs[] = {(void*)&x, (void*)&w0, (void*)&w1, (void*)&w2, (void*)&w3,
                         (void*)&w4, (void*)&w5, (void*)&w6, (void*)&wsp, (void*)&out};
        hipError_t ce = hipLaunchCooperativeKernel((const void*)conv7_kernel,
                                                   dim3(1024), dim3(256), kargs, 0, stream);
        if (ce != hipSuccess) {
            // cooperative path unavailable: proven two-pass pipeline
            prep2_kernel<<<4103, 256, 0, stream>>>(x, w0, w1, w2, w3, w4, w5, w6, wsp);
            conv5_kernel<<<1024, 256, 0, stream>>>(wsp + 7 * 4096, wsp, out);
        }
    } else if (d_ws != nullptr && ws_size >= need_w) {
        unsigned short* wsp = (unsigned short*)d_ws;
        wprep_kernel<<<7, 256, 0, stream>>>(w0, w1, w2, w3, w4, w5, w6, wsp);
        conv_kernel<<<1024, 256, 0, stream>>>(x, wsp, out);
    } else {
        fallback_kernel<<<8 * 16 * 128, 256, 0, stream>>>(x, w0, w1, w2, w3, w4, w5, w6, out);
    }
}

// Round 7
// 159.844 us; speedup vs baseline: 2.3657x; 2.3657x over previous
//
#include <hip/hip_runtime.h>

// DirectionalConv3d: B=8, C_IN=C_OUT=64, T=R=32, CO=32
// v8 design:
//  pass 1 (prep2): x fp32 [b][ch][s] -> bf16 [b][s][ch] in d_ws (+ bf16 weights).
//  pass 2 (conv8): persistent-in-t pipelined blocks.
//    grid 256 = 8 b x 32 rc-slices (1 block/CU, XCD-pinned). Block 256 thr =
//    4 waves (2 sh x 2 oh); wave = 16 rows x 32 o, acc[1][2].
//    4-slot LDS ring of 96-row slabs (48 KB): iteration t computes from slabs
//    {t-1,t,t+1} while DMA of slab t+2 is in flight (drained by the end-of-iter
//    barrier). ALL 7 taps read LDS; 28 B-frags preloaded to 112 VGPRs ONCE,
//    amortized over 32 iterations. Zero global loads in the steady-state
//    compute path. __launch_bounds__(256,2): VGPR cap 256 (no spill/starve).
// Tier 2 fallback: fused LDS kernel reading fp32 x (ws >= 56KB only).
// Tier 3 fallback: fp32 direct.

#define SB 32768   // spatial per batch (T*R*CO)
#define CIN 64
#define COUT 64
#define NB 8

typedef short s16x8 __attribute__((ext_vector_type(8)));
typedef __bf16 bf16x8 __attribute__((ext_vector_type(8)));
typedef float f32x4 __attribute__((ext_vector_type(4)));

__device__ __forceinline__ unsigned f2bf(float f) {
    unsigned u = __float_as_uint(f);
    u += 0x7FFFu + ((u >> 16) & 1u);   // round-to-nearest-even
    return u >> 16;
}
__device__ __forceinline__ unsigned pk2(float lo, float hi) {
    return f2bf(lo) | (f2bf(hi) << 16);
}

__device__ __forceinline__ void gload_lds16(const void* g, void* l) {
    __builtin_amdgcn_global_load_lds(
        (const __attribute__((address_space(1))) void*)g,
        (__attribute__((address_space(3))) void*)l, 16, 0, 0);
}

// ---------------- pass 1: weights + x transpose/convert (LDS-free) ----------------
// grid 4103 = 4096 x-blocks + 7 weight taps (proven kernel, unchanged).
__global__ __launch_bounds__(256) void prep2_kernel(const float* __restrict__ x,
                            const float* __restrict__ w0, const float* __restrict__ w1,
                            const float* __restrict__ w2, const float* __restrict__ w3,
                            const float* __restrict__ w4, const float* __restrict__ w5,
                            const float* __restrict__ w6,
                            unsigned short* __restrict__ ws) {
    int bid = blockIdx.x;
    int tid = threadIdx.x;
    if (bid >= 4096) {                 // weight blocks
        int tap = bid - 4096;
        const float* w = (tap == 0) ? w0 : (tap == 1) ? w1 : (tap == 2) ? w2
                       : (tap == 3) ? w3 : (tap == 4) ? w4 : (tap == 5) ? w5 : w6;
        unsigned p[8];
#pragma unroll
        for (int j = 0; j < 8; ++j)
            p[j] = pk2(w[tid * 16 + 2 * j], w[tid * 16 + 2 * j + 1]);
        uint4* dp = (uint4*)(ws + tap * 4096 + tid * 16);
        dp[0] = make_uint4(p[0], p[1], p[2], p[3]);
        dp[1] = make_uint4(p[4], p[5], p[6], p[7]);
        return;
    }
    int lbid = ((bid & 7) << 9) | (bid >> 3);   // bijective: 4096 % 8 == 0
    int b = lbid >> 9;                          // batch = XCD
    int i = (lbid & 511) * 256 + tid;           // [0, 131072) per batch
    int cg = i & 7;                             // channel group (8 ch)
    int s = (i >> 3) * 2;                       // even spatial row
    const float* xb = x + (size_t)b * CIN * SB;
    unsigned short* xq = ws + 7 * 4096;
    unsigned pa[4], pb[4];
#pragma unroll
    for (int u = 0; u < 4; ++u) {
        int ch = cg * 8 + 2 * u;
        float2 v0 = *(const float2*)(xb + (size_t)ch * SB + s);
        float2 v1 = *(const float2*)(xb + (size_t)(ch + 1) * SB + s);
        pa[u] = pk2(v0.x, v1.x);
        pb[u] = pk2(v0.y, v1.y);
    }
    uint4* dst = (uint4*)(xq + ((size_t)b * SB + s) * 64 + cg * 8);
    dst[0] = make_uint4(pa[0], pa[1], pa[2], pa[3]);   // row s
    dst[8] = make_uint4(pb[0], pb[1], pb[2], pb[3]);   // row s+1 (+128B)
}

// ---------------- pass 2: persistent-in-t pipelined conv ----------------
// Block owns rc-slice [rc0, rc0+32) of batch b; iterates t = 0..31.
// Slab(t) = rows rc0-32..rc0+63 (clamped) of t-slice, 96 rows x 128 B = 12 KB,
// 16B chunks source-pre-swizzled (col ^ (row&7)); ring of 4 slabs in LDS.
__global__ __launch_bounds__(256, 2) void conv8_kernel(const unsigned short* __restrict__ xq,
                                                       const unsigned short* __restrict__ wq,
                                                       float* __restrict__ out) {
    __shared__ uint4 ring[4][768];     // 48 KB
    int bid = blockIdx.x;
    int b = bid & 7;                   // batch = XCD (round-robin dispatch)
    int rc0 = (bid >> 3) << 5;         // rc-slice base, 0..992
    int tid = threadIdx.x;
    int lane = tid & 63;
    int wv = tid >> 6;                 // 0..3
    int lo = lane & 15;
    int quad = lane >> 4;
    int oh = wv & 1;                   // o-half (32 outputs)
    int sh = wv >> 1;                  // row-half (16 rows)
    const uint4* xch = (const uint4*)(xq + (size_t)b * (CIN * SB));

    // ---- B preload: 28 frags (o-half) -> 112 VGPRs, reused for all 32 t ----
    bf16x8 bq[7][2][2];
#pragma unroll
    for (int tap = 0; tap < 7; ++tap)
#pragma unroll
        for (int ks = 0; ks < 2; ++ks)
#pragma unroll
            for (int nt = 0; nt < 2; ++nt) {
                const unsigned short* bp = wq + tap * 4096
                    + (oh * 32 + nt * 16 + lo) * 64 + ks * 32 + quad * 8;
                bq[tap][ks][nt] = __builtin_bit_cast(bf16x8, *(const s16x8*)bp);
            }

    // lane geometry (t-invariant)
    int rc = rc0 + sh * 16 + lo;       // output row's rc in [0,1024)
    int rl = 32 + sh * 16 + lo;        // local slab row in [32,64)
    int r = (rc >> 5) & 31;
    int c = rc & 31;
    bool okrm = (r > 0), okrp = (r < 31), okcm = (c > 0), okcp = (c < 31);

    // stage slab for t-slice ts into ring slot k: 768 chunks, 3 DMA/thread.
    // LDS dest linear (base + lane*16); source col pre-swizzled.
    auto stage = [&](int ts, int k) {
#pragma unroll
        for (int j = 0; j < 3; ++j) {
            int cid = j * 256 + tid;               // 0..767
            int rw = cid >> 3;                     // slab row 0..95
            int sc = cid & 7;
            int rcx = rc0 - 32 + rw;
            rcx = rcx < 0 ? 0 : (rcx > 1023 ? 1023 : rcx);  // clamped rows feed masked lanes only
            const uint4* g = xch + ((size_t)(ts * 1024 + rcx) << 3) + (sc ^ (rw & 7));
            gload_lds16((const void*)g, (void*)(&ring[k][j * 256 + (wv << 6)]));
        }
    };

    const s16x8 zz = {0, 0, 0, 0, 0, 0, 0, 0};
    f32x4 acc0, acc1;

    // one tap from LDS slab: 2 ds_read_b128 + 4 MFMA (per-lane scalar mask)
    auto tap_lds = [&](const uint4* slab, const bf16x8 (&bt)[2][2], int d, bool ok) {
#pragma unroll
        for (int ks = 0; ks < 2; ++ks) {
            int row = rl + d;                      // always in [0,96)
            s16x8 a = *((const s16x8*)slab + row * 8 + ((ks * 4 + quad) ^ (row & 7)));
            a = ok ? a : zz;
            bf16x8 af = __builtin_bit_cast(bf16x8, a);
            acc0 = __builtin_amdgcn_mfma_f32_16x16x32_bf16(af, bt[ks][0], acc0, 0, 0, 0);
            acc1 = __builtin_amdgcn_mfma_f32_16x16x32_bf16(af, bt[ks][1], acc1, 0, 0, 0);
        }
    };

    // ---- prologue: slabs for t=0,1 ----
    stage(0, 0);
    stage(1, 1);
    __syncthreads();                   // drains vmcnt(0)

    for (int t = 0; t < 32; ++t) {
        if (t + 2 < 32) stage(t + 2, (t + 2) & 3);   // prefetch; drains at iter-end barrier

        acc0 = (f32x4){0.f, 0.f, 0.f, 0.f};
        acc1 = (f32x4){0.f, 0.f, 0.f, 0.f};
        const uint4* sc_ = &ring[t & 3][0];

        tap_lds(sc_, bq[0], 0, true);                          // self
        if (t > 0)  tap_lds(&ring[(t - 1) & 3][0], bq[1], 0, true);   // t-1
        if (t < 31) tap_lds(&ring[(t + 1) & 3][0], bq[2], 0, true);   // t+1
        tap_lds(sc_, bq[3], -32, okrm);                        // r-1
        tap_lds(sc_, bq[4], 32, okrp);                         // r+1
        tap_lds(sc_, bq[5], -1, okcm);                         // c-1
        tap_lds(sc_, bq[6], 1, okcp);                          // c+1

        // D layout: col(o) = lane&15, row = quad*4 + reg
        size_t ob = ((size_t)(b * COUT + oh * 32 + lo)) * SB
                  + (size_t)t * 1024 + rc0 + sh * 16 + quad * 4;
        *(f32x4*)(out + ob) = acc0;                 // nt = 0
        *(f32x4*)(out + ob + (size_t)16 * SB) = acc1;   // nt = 1 (o += 16)

        __syncthreads();               // slab t+2 landed; ring slot (t-2)&3 reusable
    }
}

// ---------------- tier-2 fallback: weights only ----------------
__global__ __launch_bounds__(256) void wprep_kernel(const float* __restrict__ w0,
                            const float* __restrict__ w1, const float* __restrict__ w2,
                            const float* __restrict__ w3, const float* __restrict__ w4,
                            const float* __restrict__ w5, const float* __restrict__ w6,
                            unsigned short* __restrict__ ws) {
    int tap = blockIdx.x;
    int tid = threadIdx.x;
    const float* w = (tap == 0) ? w0 : (tap == 1) ? w1 : (tap == 2) ? w2
                   : (tap == 3) ? w3 : (tap == 4) ? w4 : (tap == 5) ? w5 : w6;
    unsigned p[8];
#pragma unroll
    for (int j = 0; j < 8; ++j)
        p[j] = pk2(w[tid * 16 + 2 * j], w[tid * 16 + 2 * j + 1]);
    uint4* dp = (uint4*)(ws + tap * 4096 + tid * 16);
    dp[0] = make_uint4(p[0], p[1], p[2], p[3]);
    dp[1] = make_uint4(p[4], p[5], p[6], p[7]);
}

// ---------------- tier-2 fallback: fused LDS kernel on fp32 x ----------------
__global__ __launch_bounds__(256) void conv_kernel(const float* __restrict__ x,
                                                   const unsigned short* __restrict__ wq,
                                                   float* __restrict__ out) {
    __shared__ uint4 alds[2560];
    int bid = blockIdx.x;
    int b = bid >> 7;
    int sblk = (bid & 127) << 8;
    int tid = threadIdx.x;
    const float* xb = x + (size_t)b * CIN * SB;

    {
        int rl = 32 + tid;
        const float* xp = xb + sblk + tid;
#pragma unroll
        for (int c = 0; c < 4; ++c) {
            unsigned pk[8];
#pragma unroll
            for (int u = 0; u < 8; ++u)
                pk[u] = pk2(xp[(size_t)(c * 16 + 2 * u) * SB],
                            xp[(size_t)(c * 16 + 2 * u + 1) * SB]);
            alds[rl * 8 + ((2 * c) ^ (rl & 7))] = make_uint4(pk[0], pk[1], pk[2], pk[3]);
            alds[rl * 8 + ((2 * c + 1) ^ (rl & 7))] = make_uint4(pk[4], pk[5], pk[6], pk[7]);
        }
    }
    {
        int hrow = tid & 63;
        int rl = (hrow < 32) ? hrow : hrow + 256;
        int s = sblk - 32 + rl;
        s = max(0, min(SB - 1, s));
        int ic = tid >> 6;
        const float* xp = xb + s + (size_t)(ic * 16) * SB;
        unsigned pk[8];
#pragma unroll
        for (int u = 0; u < 8; ++u)
            pk[u] = pk2(xp[(size_t)(2 * u) * SB], xp[(size_t)(2 * u + 1) * SB]);
        alds[rl * 8 + ((2 * ic) ^ (rl & 7))] = make_uint4(pk[0], pk[1], pk[2], pk[3]);
        alds[rl * 8 + ((2 * ic + 1) ^ (rl & 7))] = make_uint4(pk[4], pk[5], pk[6], pk[7]);
    }
    __syncthreads();

    int lane = tid & 63;
    int wv = tid >> 6;
    int lo = lane & 15;
    int quad = lane >> 4;
    int sbase = sblk + wv * 64;
    int t = sblk >> 10;

    f32x4 acc[4][4];
#pragma unroll
    for (int mt = 0; mt < 4; ++mt)
#pragma unroll
        for (int nt = 0; nt < 4; ++nt)
            acc[mt][nt] = (f32x4){0.f, 0.f, 0.f, 0.f};

    int r_m[4], c_m[4], rl[4];
#pragma unroll
    for (int mt = 0; mt < 4; ++mt) {
        int s = sbase + mt * 16 + lo;
        r_m[mt] = (s >> 5) & 31;
        c_m[mt] = s & 31;
        rl[mt] = s - sblk + 32;
    }

    auto load_b = [&](const unsigned short* wt, int ks, int nt) -> bf16x8 {
        const unsigned short* bp = wt + (nt * 16 + lo) * 64 + ks * 32 + quad * 8;
        return __builtin_bit_cast(bf16x8, *(const s16x8*)bp);
    };

    auto run_tap_lds = [&](int tap, int d, const bool ok[4]) {
        const unsigned short* wt = wq + tap * 4096;
#pragma unroll
        for (int ks = 0; ks < 2; ++ks) {
            bf16x8 bf[4];
#pragma unroll
            for (int nt = 0; nt < 4; ++nt) bf[nt] = load_b(wt, ks, nt);
            int j = ks * 4 + quad;
#pragma unroll
            for (int mt = 0; mt < 4; ++mt) {
                int row = rl[mt] + d;
                s16x8 raw = *((const s16x8*)alds + row * 8 + (j ^ (row & 7)));
                s16x8 zx = {0, 0, 0, 0, 0, 0, 0, 0};
                raw = ok[mt] ? raw : zx;
                bf16x8 af = __builtin_bit_cast(bf16x8, raw);
#pragma unroll
                for (int nt = 0; nt < 4; ++nt)
                    acc[mt][nt] = __builtin_amdgcn_mfma_f32_16x16x32_bf16(af, bf[nt], acc[mt][nt], 0, 0, 0);
            }
        }
    };

    auto run_tap_gather = [&](int tap, int d) {
        const unsigned short* wt = wq + tap * 4096;
#pragma unroll
        for (int ks = 0; ks < 2; ++ks) {
            bf16x8 bf[4];
#pragma unroll
            for (int nt = 0; nt < 4; ++nt) bf[nt] = load_b(wt, ks, nt);
            const float* gp = xb + (size_t)(ks * 32 + quad * 8) * SB + d;
#pragma unroll
            for (int mt = 0; mt < 4; ++mt) {
                const float* ap = gp + sbase + mt * 16 + lo;
                unsigned pk[4];
#pragma unroll
                for (int u = 0; u < 4; ++u)
                    pk[u] = pk2(ap[(size_t)(2 * u) * SB], ap[(size_t)(2 * u + 1) * SB]);
                uint4 v = make_uint4(pk[0], pk[1], pk[2], pk[3]);
                bf16x8 af = __builtin_bit_cast(bf16x8, v);
#pragma unroll
                for (int nt = 0; nt < 4; ++nt)
                    acc[mt][nt] = __builtin_amdgcn_mfma_f32_16x16x32_bf16(af, bf[nt], acc[mt][nt], 0, 0, 0);
            }
        }
    };

    {
        bool ok_all[4] = {true, true, true, true};
        run_tap_lds(0, 0, ok_all);
    }
    if (t > 0)  run_tap_gather(1, -1024);
    if (t < 31) run_tap_gather(2, 1024);
    {
        bool ok[4];
#pragma unroll
        for (int mt = 0; mt < 4; ++mt) ok[mt] = (r_m[mt] > 0);
        run_tap_lds(3, -32, ok);
#pragma unroll
        for (int mt = 0; mt < 4; ++mt) ok[mt] = (r_m[mt] < 31);
        run_tap_lds(4, 32, ok);
#pragma unroll
        for (int mt = 0; mt < 4; ++mt) ok[mt] = (c_m[mt] > 0);
        run_tap_lds(5, -1, ok);
#pragma unroll
        for (int mt = 0; mt < 4; ++mt) ok[mt] = (c_m[mt] < 31);
        run_tap_lds(6, 1, ok);
    }

#pragma unroll
    for (int mt = 0; mt < 4; ++mt) {
#pragma unroll
        for (int nt = 0; nt < 4; ++nt) {
            int o = nt * 16 + lo;
            size_t off = ((size_t)(b * COUT + o)) * SB + sbase + mt * 16 + quad * 4;
            *(f32x4*)(out + off) = acc[mt][nt];
        }
    }
}

// ---------------- tier-3 fallback: fp32 direct ----------------
__global__ void fallback_kernel(const float* __restrict__ x,
                                const float* __restrict__ w0, const float* __restrict__ w1,
                                const float* __restrict__ w2, const float* __restrict__ w3,
                                const float* __restrict__ w4, const float* __restrict__ w5,
                                const float* __restrict__ w6,
                                float* __restrict__ out) {
    int bid = blockIdx.x;
    int b = bid >> 11;
    int og = (bid >> 7) & 15;
    int sblk = (bid & 127) << 8;
    int tid = threadIdx.x;
    __shared__ float wl[7][4][64];
    const float* wp[7] = {w0, w1, w2, w3, w4, w5, w6};
    for (int k = tid; k < 7 * 4 * 64; k += 256) {
        int tap = k >> 8, oo = (k >> 6) & 3, i = k & 63;
        wl[tap][oo][i] = wp[tap][(og * 4 + oo) * 64 + i];
    }
    __syncthreads();
    int s = sblk + tid;
    int t = s >> 10, r = (s >> 5) & 31, c = s & 31;
    const float* xb = x + (size_t)b * CIN * SB + s;
    float a0 = 0, a1 = 0, a2 = 0, a3 = 0;
    for (int i = 0; i < 64; ++i) {
        const float* xi = xb + (size_t)i * SB;
        float vs = xi[0];
        float vtp = (t > 0) ? xi[-1024] : 0.f;
        float vtm = (t < 31) ? xi[1024] : 0.f;
        float vrp = (r > 0) ? xi[-32] : 0.f;
        float vrm = (r < 31) ? xi[32] : 0.f;
        float vcp = (c > 0) ? xi[-1] : 0.f;
        float vcm = (c < 31) ? xi[1] : 0.f;
        a0 += wl[0][0][i] * vs + wl[1][0][i] * vtp + wl[2][0][i] * vtm + wl[3][0][i] * vrp + wl[4][0][i] * vrm + wl[5][0][i] * vcp + wl[6][0][i] * vcm;
        a1 += wl[0][1][i] * vs + wl[1][1][i] * vtp + wl[2][1][i] * vtm + wl[3][1][i] * vrp + wl[4][1][i] * vrm + wl[5][1][i] * vcp + wl[6][1][i] * vcm;
        a2 += wl[0][2][i] * vs + wl[1][2][i] * vtp + wl[2][2][i] * vtm + wl[3][2][i] * vrp + wl[4][2][i] * vrm + wl[5][2][i] * vcp + wl[6][2][i] * vcm;
        a3 += wl[0][3][i] * vs + wl[1][3][i] * vtp + wl[2][3][i] * vtm + wl[3][3][i] * vrp + wl[4][3][i] * vrm + wl[5][3][i] * vcp + wl[6][3][i] * vcm;
    }
    size_t obase = ((size_t)b * COUT + og * 4) * SB + s;
    out[obase] = a0;
    out[obase + SB] = a1;
    out[obase + 2 * (size_t)SB] = a2;
    out[obase + 3 * (size_t)SB] = a3;
}

extern "C" void kernel_launch(void* const* d_in, const int* in_sizes, int n_in,
                              void* d_out, int out_size, void* d_ws, size_t ws_size,
                              hipStream_t stream) {
    const float* x = (const float*)d_in[0];
    const float* w0 = (const float*)d_in[1];
    const float* w1 = (const float*)d_in[2];
    const float* w2 = (const float*)d_in[3];
    const float* w3 = (const float*)d_in[4];
    const float* w4 = (const float*)d_in[5];
    const float* w5 = (const float*)d_in[6];
    const float* w6 = (const float*)d_in[7];
    float* out = (float*)d_out;

    size_t need_w = (size_t)7 * 4096 * 2;                        // 56 KB weights
    size_t need_full = need_w + (size_t)NB * CIN * SB * 2;       // + 32 MB bf16 x
    if (d_ws != nullptr && ws_size >= need_full) {
        unsigned short* wsp = (unsigned short*)d_ws;
        prep2_kernel<<<4103, 256, 0, stream>>>(x, w0, w1, w2, w3, w4, w5, w6, wsp);
        conv8_kernel<<<256, 256, 0, stream>>>(wsp + 7 * 4096, wsp, out);
    } else if (d_ws != nullptr && ws_size >= need_w) {
        unsigned short* wsp = (unsigned short*)d_ws;
        wprep_kernel<<<7, 256, 0, stream>>>(w0, w1, w2, w3, w4, w5, w6, wsp);
        conv_kernel<<<1024, 256, 0, stream>>>(x, wsp, out);
    } else {
        fallback_kernel<<<8 * 16 * 128, 256, 0, stream>>>(x, w0, w1, w2, w3, w4, w5, w6, out);
    }
}

// Round 8
// 157.993 us; speedup vs baseline: 2.3934x; 1.0117x over previous
//
#include <hip/hip_runtime.h>

// DirectionalConv3d: B=8, C_IN=C_OUT=64, T=R=32, CO=32
// v9 design:
//  pass 1 (prep2): x fp32 [b][ch][s] -> bf16 [b][s][ch] in d_ws (+ bf16 weights).
//  pass 2 (conv9): persistent-in-t pipelined blocks, 2 blocks/CU.
//    grid 512 = 8 b x 64 rc-slices of 16 rows (XCD-pinned). Block 256 thr =
//    4 waves (on = wv); wave = 16 rows x 16 o, single f32x4 acc.
//    4-slot LDS ring of 80-row slabs (40 KB); iteration t computes slabs
//    {t-1,t,t+1} while slab t+2 DMA is in flight. 2 blocks/CU -> 2 waves/SIMD
//    AND independent barrier domains: one block computes while the other
//    stages/drains (the lever conv8 lacked at 1 block/CU).
//    14 B-frags/wave preloaded once (56 VGPR), amortized over 32 t.
// Tier 2 fallback: fused LDS kernel reading fp32 x (ws >= 56KB only).
// Tier 3 fallback: fp32 direct.

#define SB 32768   // spatial per batch (T*R*CO)
#define CIN 64
#define COUT 64
#define NB 8

typedef short s16x8 __attribute__((ext_vector_type(8)));
typedef __bf16 bf16x8 __attribute__((ext_vector_type(8)));
typedef float f32x4 __attribute__((ext_vector_type(4)));

__device__ __forceinline__ unsigned f2bf(float f) {
    unsigned u = __float_as_uint(f);
    u += 0x7FFFu + ((u >> 16) & 1u);   // round-to-nearest-even
    return u >> 16;
}
__device__ __forceinline__ unsigned pk2(float lo, float hi) {
    return f2bf(lo) | (f2bf(hi) << 16);
}

__device__ __forceinline__ void gload_lds16(const void* g, void* l) {
    __builtin_amdgcn_global_load_lds(
        (const __attribute__((address_space(1))) void*)g,
        (__attribute__((address_space(3))) void*)l, 16, 0, 0);
}

// ---------------- pass 1: weights + x transpose/convert (LDS-free) ----------------
// grid 4103 = 4096 x-blocks + 7 weight taps (proven kernel, unchanged).
__global__ __launch_bounds__(256) void prep2_kernel(const float* __restrict__ x,
                            const float* __restrict__ w0, const float* __restrict__ w1,
                            const float* __restrict__ w2, const float* __restrict__ w3,
                            const float* __restrict__ w4, const float* __restrict__ w5,
                            const float* __restrict__ w6,
                            unsigned short* __restrict__ ws) {
    int bid = blockIdx.x;
    int tid = threadIdx.x;
    if (bid >= 4096) {                 // weight blocks
        int tap = bid - 4096;
        const float* w = (tap == 0) ? w0 : (tap == 1) ? w1 : (tap == 2) ? w2
                       : (tap == 3) ? w3 : (tap == 4) ? w4 : (tap == 5) ? w5 : w6;
        unsigned p[8];
#pragma unroll
        for (int j = 0; j < 8; ++j)
            p[j] = pk2(w[tid * 16 + 2 * j], w[tid * 16 + 2 * j + 1]);
        uint4* dp = (uint4*)(ws + tap * 4096 + tid * 16);
        dp[0] = make_uint4(p[0], p[1], p[2], p[3]);
        dp[1] = make_uint4(p[4], p[5], p[6], p[7]);
        return;
    }
    int lbid = ((bid & 7) << 9) | (bid >> 3);   // bijective: 4096 % 8 == 0
    int b = lbid >> 9;                          // batch = XCD
    int i = (lbid & 511) * 256 + tid;           // [0, 131072) per batch
    int cg = i & 7;                             // channel group (8 ch)
    int s = (i >> 3) * 2;                       // even spatial row
    const float* xb = x + (size_t)b * CIN * SB;
    unsigned short* xq = ws + 7 * 4096;
    unsigned pa[4], pb[4];
#pragma unroll
    for (int u = 0; u < 4; ++u) {
        int ch = cg * 8 + 2 * u;
        float2 v0 = *(const float2*)(xb + (size_t)ch * SB + s);
        float2 v1 = *(const float2*)(xb + (size_t)(ch + 1) * SB + s);
        pa[u] = pk2(v0.x, v1.x);
        pb[u] = pk2(v0.y, v1.y);
    }
    uint4* dst = (uint4*)(xq + ((size_t)b * SB + s) * 64 + cg * 8);
    dst[0] = make_uint4(pa[0], pa[1], pa[2], pa[3]);   // row s
    dst[8] = make_uint4(pb[0], pb[1], pb[2], pb[3]);   // row s+1 (+128B)
}

// ---------------- pass 2: persistent-in-t pipelined conv, 2 blocks/CU ----------------
// Block owns rc-slice [rc0, rc0+16) of batch b; iterates t = 0..31.
// Slab(t) = rows rc0-32..rc0+47 (clamped), 80 rows x 128 B = 10 KB,
// 16B chunks source-pre-swizzled (col ^ (row&7)); ring of 4 slabs (40 KB).
__global__ __launch_bounds__(256, 2) void conv9_kernel(const unsigned short* __restrict__ xq,
                                                       const unsigned short* __restrict__ wq,
                                                       float* __restrict__ out) {
    __shared__ uint4 ring[4][640];     // 40 KB
    int bid = blockIdx.x;
    int b = bid & 7;                   // batch = XCD (round-robin dispatch)
    int rc0 = (bid >> 3) << 4;         // rc-slice base, 0..1008
    int tid = threadIdx.x;
    int lane = tid & 63;
    int wv = tid >> 6;                 // 0..3 = o-tile index
    int lo = lane & 15;
    int quad = lane >> 4;
    const uint4* xch = (const uint4*)(xq + (size_t)b * (CIN * SB));

    // ---- B preload: 14 frags (o-tile wv) -> 56 VGPRs, reused for all 32 t ----
    bf16x8 bq[7][2];
#pragma unroll
    for (int tap = 0; tap < 7; ++tap)
#pragma unroll
        for (int ks = 0; ks < 2; ++ks) {
            const unsigned short* bp = wq + tap * 4096
                + (wv * 16 + lo) * 64 + ks * 32 + quad * 8;
            bq[tap][ks] = __builtin_bit_cast(bf16x8, *(const s16x8*)bp);
        }

    // lane geometry (t-invariant)
    int rc = rc0 + lo;                 // output row's rc in [0,1024)
    int rl = 32 + lo;                  // local slab row in [32,48)
    int r = (rc >> 5) & 31;
    int c = rc & 31;
    bool okrm = (r > 0), okrp = (r < 31), okcm = (c > 0), okcp = (c < 31);

    // stage slab for t-slice ts into ring slot k: 640 chunks, waves 0-3 x2 + waves 0-1 x1.
    // LDS dest linear (base + lane*16); source col pre-swizzled.
    auto stage = [&](int ts, int k) {
#pragma unroll
        for (int j = 0; j < 2; ++j) {
            int cid = j * 256 + tid;               // 0..511
            int rw = cid >> 3;                     // slab row
            int sc = cid & 7;
            int rcx = rc0 - 32 + rw;
            rcx = rcx < 0 ? 0 : (rcx > 1023 ? 1023 : rcx);  // clamped rows feed masked lanes only
            const uint4* g = xch + ((size_t)(ts * 1024 + rcx) << 3) + (sc ^ (rw & 7));
            gload_lds16((const void*)g, (void*)(&ring[k][j * 256 + (wv << 6)]));
        }
        if (wv < 2) {                              // chunks 512..639 (rows 64..79)
            int cid = 512 + tid;
            int rw = cid >> 3;
            int sc = cid & 7;
            int rcx = rc0 - 32 + rw;
            rcx = rcx > 1023 ? 1023 : rcx;
            const uint4* g = xch + ((size_t)(ts * 1024 + rcx) << 3) + (sc ^ (rw & 7));
            gload_lds16((const void*)g, (void*)(&ring[k][512 + (wv << 6)]));
        }
    };

    const s16x8 zz = {0, 0, 0, 0, 0, 0, 0, 0};
    f32x4 acc;

    // one tap from LDS slab: 2 ds_read_b128 + 2 MFMA (per-lane scalar mask)
    auto tap_lds = [&](const uint4* slab, const bf16x8 (&bt)[2], int d, bool ok) {
#pragma unroll
        for (int ks = 0; ks < 2; ++ks) {
            int row = rl + d;                      // always in [0,80)
            s16x8 a = *((const s16x8*)slab + row * 8 + ((ks * 4 + quad) ^ (row & 7)));
            a = ok ? a : zz;
            bf16x8 af = __builtin_bit_cast(bf16x8, a);
            acc = __builtin_amdgcn_mfma_f32_16x16x32_bf16(af, bt[ks], acc, 0, 0, 0);
        }
    };

    // ---- prologue: slabs for t=0,1 ----
    stage(0, 0);
    stage(1, 1);
    __syncthreads();                   // drains vmcnt(0)

    for (int t = 0; t < 32; ++t) {
        if (t + 2 < 32) stage(t + 2, (t + 2) & 3);   // prefetch; drains at iter-end barrier

        acc = (f32x4){0.f, 0.f, 0.f, 0.f};
        const uint4* sc_ = &ring[t & 3][0];

        tap_lds(sc_, bq[0], 0, true);                          // self
        if (t > 0)  tap_lds(&ring[(t - 1) & 3][0], bq[1], 0, true);   // t-1
        if (t < 31) tap_lds(&ring[(t + 1) & 3][0], bq[2], 0, true);   // t+1
        tap_lds(sc_, bq[3], -32, okrm);                        // r-1
        tap_lds(sc_, bq[4], 32, okrp);                         // r+1
        tap_lds(sc_, bq[5], -1, okcm);                         // c-1
        tap_lds(sc_, bq[6], 1, okcp);                          // c+1

        // D layout: col(o) = lane&15, row = quad*4 + reg
        size_t ob = ((size_t)(b * COUT + wv * 16 + lo)) * SB
                  + (size_t)t * 1024 + rc0 + quad * 4;
        *(f32x4*)(out + ob) = acc;

        __syncthreads();               // slab t+2 landed; ring slot (t-2)&3 reusable
    }
}

// ---------------- tier-2 fallback: weights only ----------------
__global__ __launch_bounds__(256) void wprep_kernel(const float* __restrict__ w0,
                            const float* __restrict__ w1, const float* __restrict__ w2,
                            const float* __restrict__ w3, const float* __restrict__ w4,
                            const float* __restrict__ w5, const float* __restrict__ w6,
                            unsigned short* __restrict__ ws) {
    int tap = blockIdx.x;
    int tid = threadIdx.x;
    const float* w = (tap == 0) ? w0 : (tap == 1) ? w1 : (tap == 2) ? w2
                   : (tap == 3) ? w3 : (tap == 4) ? w4 : (tap == 5) ? w5 : w6;
    unsigned p[8];
#pragma unroll
    for (int j = 0; j < 8; ++j)
        p[j] = pk2(w[tid * 16 + 2 * j], w[tid * 16 + 2 * j + 1]);
    uint4* dp = (uint4*)(ws + tap * 4096 + tid * 16);
    dp[0] = make_uint4(p[0], p[1], p[2], p[3]);
    dp[1] = make_uint4(p[4], p[5], p[6], p[7]);
}

// ---------------- tier-2 fallback: fused LDS kernel on fp32 x ----------------
__global__ __launch_bounds__(256) void conv_kernel(const float* __restrict__ x,
                                                   const unsigned short* __restrict__ wq,
                                                   float* __restrict__ out) {
    __shared__ uint4 alds[2560];
    int bid = blockIdx.x;
    int b = bid >> 7;
    int sblk = (bid & 127) << 8;
    int tid = threadIdx.x;
    const float* xb = x + (size_t)b * CIN * SB;

    {
        int rl = 32 + tid;
        const float* xp = xb + sblk + tid;
#pragma unroll
        for (int c = 0; c < 4; ++c) {
            unsigned pk[8];
#pragma unroll
            for (int u = 0; u < 8; ++u)
                pk[u] = pk2(xp[(size_t)(c * 16 + 2 * u) * SB],
                            xp[(size_t)(c * 16 + 2 * u + 1) * SB]);
            alds[rl * 8 + ((2 * c) ^ (rl & 7))] = make_uint4(pk[0], pk[1], pk[2], pk[3]);
            alds[rl * 8 + ((2 * c + 1) ^ (rl & 7))] = make_uint4(pk[4], pk[5], pk[6], pk[7]);
        }
    }
    {
        int hrow = tid & 63;
        int rl = (hrow < 32) ? hrow : hrow + 256;
        int s = sblk - 32 + rl;
        s = max(0, min(SB - 1, s));
        int ic = tid >> 6;
        const float* xp = xb + s + (size_t)(ic * 16) * SB;
        unsigned pk[8];
#pragma unroll
        for (int u = 0; u < 8; ++u)
            pk[u] = pk2(xp[(size_t)(2 * u) * SB], xp[(size_t)(2 * u + 1) * SB]);
        alds[rl * 8 + ((2 * ic) ^ (rl & 7))] = make_uint4(pk[0], pk[1], pk[2], pk[3]);
        alds[rl * 8 + ((2 * ic + 1) ^ (rl & 7))] = make_uint4(pk[4], pk[5], pk[6], pk[7]);
    }
    __syncthreads();

    int lane = tid & 63;
    int wv = tid >> 6;
    int lo = lane & 15;
    int quad = lane >> 4;
    int sbase = sblk + wv * 64;
    int t = sblk >> 10;

    f32x4 acc[4][4];
#pragma unroll
    for (int mt = 0; mt < 4; ++mt)
#pragma unroll
        for (int nt = 0; nt < 4; ++nt)
            acc[mt][nt] = (f32x4){0.f, 0.f, 0.f, 0.f};

    int r_m[4], c_m[4], rl[4];
#pragma unroll
    for (int mt = 0; mt < 4; ++mt) {
        int s = sbase + mt * 16 + lo;
        r_m[mt] = (s >> 5) & 31;
        c_m[mt] = s & 31;
        rl[mt] = s - sblk + 32;
    }

    auto load_b = [&](const unsigned short* wt, int ks, int nt) -> bf16x8 {
        const unsigned short* bp = wt + (nt * 16 + lo) * 64 + ks * 32 + quad * 8;
        return __builtin_bit_cast(bf16x8, *(const s16x8*)bp);
    };

    auto run_tap_lds = [&](int tap, int d, const bool ok[4]) {
        const unsigned short* wt = wq + tap * 4096;
#pragma unroll
        for (int ks = 0; ks < 2; ++ks) {
            bf16x8 bf[4];
#pragma unroll
            for (int nt = 0; nt < 4; ++nt) bf[nt] = load_b(wt, ks, nt);
            int j = ks * 4 + quad;
#pragma unroll
            for (int mt = 0; mt < 4; ++mt) {
                int row = rl[mt] + d;
                s16x8 raw = *((const s16x8*)alds + row * 8 + (j ^ (row & 7)));
                s16x8 zx = {0, 0, 0, 0, 0, 0, 0, 0};
                raw = ok[mt] ? raw : zx;
                bf16x8 af = __builtin_bit_cast(bf16x8, raw);
#pragma unroll
                for (int nt = 0; nt < 4; ++nt)
                    acc[mt][nt] = __builtin_amdgcn_mfma_f32_16x16x32_bf16(af, bf[nt], acc[mt][nt], 0, 0, 0);
            }
        }
    };

    auto run_tap_gather = [&](int tap, int d) {
        const unsigned short* wt = wq + tap * 4096;
#pragma unroll
        for (int ks = 0; ks < 2; ++ks) {
            bf16x8 bf[4];
#pragma unroll
            for (int nt = 0; nt < 4; ++nt) bf[nt] = load_b(wt, ks, nt);
            const float* gp = xb + (size_t)(ks * 32 + quad * 8) * SB + d;
#pragma unroll
            for (int mt = 0; mt < 4; ++mt) {
                const float* ap = gp + sbase + mt * 16 + lo;
                unsigned pk[4];
#pragma unroll
                for (int u = 0; u < 4; ++u)
                    pk[u] = pk2(ap[(size_t)(2 * u) * SB], ap[(size_t)(2 * u + 1) * SB]);
                uint4 v = make_uint4(pk[0], pk[1], pk[2], pk[3]);
                bf16x8 af = __builtin_bit_cast(bf16x8, v);
#pragma unroll
                for (int nt = 0; nt < 4; ++nt)
                    acc[mt][nt] = __builtin_amdgcn_mfma_f32_16x16x32_bf16(af, bf[nt], acc[mt][nt], 0, 0, 0);
            }
        }
    };

    {
        bool ok_all[4] = {true, true, true, true};
        run_tap_lds(0, 0, ok_all);
    }
    if (t > 0)  run_tap_gather(1, -1024);
    if (t < 31) run_tap_gather(2, 1024);
    {
        bool ok[4];
#pragma unroll
        for (int mt = 0; mt < 4; ++mt) ok[mt] = (r_m[mt] > 0);
        run_tap_lds(3, -32, ok);
#pragma unroll
        for (int mt = 0; mt < 4; ++mt) ok[mt] = (r_m[mt] < 31);
        run_tap_lds(4, 32, ok);
#pragma unroll
        for (int mt = 0; mt < 4; ++mt) ok[mt] = (c_m[mt] > 0);
        run_tap_lds(5, -1, ok);
#pragma unroll
        for (int mt = 0; mt < 4; ++mt) ok[mt] = (c_m[mt] < 31);
        run_tap_lds(6, 1, ok);
    }

#pragma unroll
    for (int mt = 0; mt < 4; ++mt) {
#pragma unroll
        for (int nt = 0; nt < 4; ++nt) {
            int o = nt * 16 + lo;
            size_t off = ((size_t)(b * COUT + o)) * SB + sbase + mt * 16 + quad * 4;
            *(f32x4*)(out + off) = acc[mt][nt];
        }
    }
}

// ---------------- tier-3 fallback: fp32 direct ----------------
__global__ void fallback_kernel(const float* __restrict__ x,
                                const float* __restrict__ w0, const float* __restrict__ w1,
                                const float* __restrict__ w2, const float* __restrict__ w3,
                                const float* __restrict__ w4, const float* __restrict__ w5,
                                const float* __restrict__ w6,
                                float* __restrict__ out) {
    int bid = blockIdx.x;
    int b = bid >> 11;
    int og = (bid >> 7) & 15;
    int sblk = (bid & 127) << 8;
    int tid = threadIdx.x;
    __shared__ float wl[7][4][64];
    const float* wp[7] = {w0, w1, w2, w3, w4, w5, w6};
    for (int k = tid; k < 7 * 4 * 64; k += 256) {
        int tap = k >> 8, oo = (k >> 6) & 3, i = k & 63;
        wl[tap][oo][i] = wp[tap][(og * 4 + oo) * 64 + i];
    }
    __syncthreads();
    int s = sblk + tid;
    int t = s >> 10, r = (s >> 5) & 31, c = s & 31;
    const float* xb = x + (size_t)b * CIN * SB + s;
    float a0 = 0, a1 = 0, a2 = 0, a3 = 0;
    for (int i = 0; i < 64; ++i) {
        const float* xi = xb + (size_t)i * SB;
        float vs = xi[0];
        float vtp = (t > 0) ? xi[-1024] : 0.f;
        float vtm = (t < 31) ? xi[1024] : 0.f;
        float vrp = (r > 0) ? xi[-32] : 0.f;
        float vrm = (r < 31) ? xi[32] : 0.f;
        float vcp = (c > 0) ? xi[-1] : 0.f;
        float vcm = (c < 31) ? xi[1] : 0.f;
        a0 += wl[0][0][i] * vs + wl[1][0][i] * vtp + wl[2][0][i] * vtm + wl[3][0][i] * vrp + wl[4][0][i] * vrm + wl[5][0][i] * vcp + wl[6][0][i] * vcm;
        a1 += wl[0][1][i] * vs + wl[1][1][i] * vtp + wl[2][1][i] * vtm + wl[3][1][i] * vrp + wl[4][1][i] * vrm + wl[5][1][i] * vcp + wl[6][1][i] * vcm;
        a2 += wl[0][2][i] * vs + wl[1][2][i] * vtp + wl[2][2][i] * vtm + wl[3][2][i] * vrp + wl[4][2][i] * vrm + wl[5][2][i] * vcp + wl[6][2][i] * vcm;
        a3 += wl[0][3][i] * vs + wl[1][3][i] * vtp + wl[2][3][i] * vtm + wl[3][3][i] * vrp + wl[4][3][i] * vrm + wl[5][3][i] * vcp + wl[6][3][i] * vcm;
    }
    size_t obase = ((size_t)b * COUT + og * 4) * SB + s;
    out[obase] = a0;
    out[obase + SB] = a1;
    out[obase + 2 * (size_t)SB] = a2;
    out[obase + 3 * (size_t)SB] = a3;
}

extern "C" void kernel_launch(void* const* d_in, const int* in_sizes, int n_in,
                              void* d_out, int out_size, void* d_ws, size_t ws_size,
                              hipStream_t stream) {
    const float* x = (const float*)d_in[0];
    const float* w0 = (const float*)d_in[1];
    const float* w1 = (const float*)d_in[2];
    const float* w2 = (const float*)d_in[3];
    const float* w3 = (const float*)d_in[4];
    const float* w4 = (const float*)d_in[5];
    const float* w5 = (const float*)d_in[6];
    const float* w6 = (const float*)d_in[7];
    float* out = (float*)d_out;

    size_t need_w = (size_t)7 * 4096 * 2;                        // 56 KB weights
    size_t need_full = need_w + (size_t)NB * CIN * SB * 2;       // + 32 MB bf16 x
    if (d_ws != nullptr && ws_size >= need_full) {
        unsigned short* wsp = (unsigned short*)d_ws;
        prep2_kernel<<<4103, 256, 0, stream>>>(x, w0, w1, w2, w3, w4, w5, w6, wsp);
        conv9_kernel<<<512, 256, 0, stream>>>(wsp + 7 * 4096, wsp, out);
    } else if (d_ws != nullptr && ws_size >= need_w) {
        unsigned short* wsp = (unsigned short*)d_ws;
        wprep_kernel<<<7, 256, 0, stream>>>(w0, w1, w2, w3, w4, w5, w6, wsp);
        conv_kernel<<<1024, 256, 0, stream>>>(x, wsp, out);
    } else {
        fallback_kernel<<<8 * 16 * 128, 256, 0, stream>>>(x, w0, w1, w2, w3, w4, w5, w6, out);
    }
}

// Round 9
// 151.467 us; speedup vs baseline: 2.4966x; 1.0431x over previous
//
#include <hip/hip_runtime.h>

// DirectionalConv3d: B=8, C_IN=C_OUT=64, T=R=32, CO=32
// v10 design:
//  pass 1 (prep2): x fp32 [b][ch][s] -> bf16 [b][s][ch] in d_ws (+ bf16 weights).
//  pass 2 (conv10): persistent-in-t ring pipeline with COUNTED vmcnt barriers.
//    grid 256 = 8 b x 32 rc-slices of 32 rows (XCD-pinned); block 512 thr =
//    8 waves (2 row-halves x 4 o-tiles); wave = 16 rows x 16 o.
//    4-slot LDS ring of 96-row slabs (48 KB); 2 blocks/CU -> 4 waves/SIMD.
//    Per iter: asm s_waitcnt vmcnt(1) [stage(t+1) done, store(t-1) stays in
//    flight] + raw s_barrier -> NO per-iter drain of stores/stage (the T4
//    lever: drain-0 barriers were the 40us floor of conv8/9).
//    Dual accumulator chains (ks 0/1) halve exposed MFMA latency.
//    14 B-frags/wave preloaded once (56 VGPR), amortized over 32 t.
// Tier 2 fallback: fused LDS kernel reading fp32 x (ws >= 56KB only).
// Tier 3 fallback: fp32 direct.

#define SB 32768   // spatial per batch (T*R*CO)
#define CIN 64
#define COUT 64
#define NB 8

typedef short s16x8 __attribute__((ext_vector_type(8)));
typedef __bf16 bf16x8 __attribute__((ext_vector_type(8)));
typedef float f32x4 __attribute__((ext_vector_type(4)));

__device__ __forceinline__ unsigned f2bf(float f) {
    unsigned u = __float_as_uint(f);
    u += 0x7FFFu + ((u >> 16) & 1u);   // round-to-nearest-even
    return u >> 16;
}
__device__ __forceinline__ unsigned pk2(float lo, float hi) {
    return f2bf(lo) | (f2bf(hi) << 16);
}

__device__ __forceinline__ void gload_lds16(const void* g, void* l) {
    __builtin_amdgcn_global_load_lds(
        (const __attribute__((address_space(1))) void*)g,
        (__attribute__((address_space(3))) void*)l, 16, 0, 0);
}

// ---------------- pass 1: weights + x transpose/convert (LDS-free) ----------------
// grid 4103 = 4096 x-blocks + 7 weight taps (proven kernel, unchanged).
__global__ __launch_bounds__(256) void prep2_kernel(const float* __restrict__ x,
                            const float* __restrict__ w0, const float* __restrict__ w1,
                            const float* __restrict__ w2, const float* __restrict__ w3,
                            const float* __restrict__ w4, const float* __restrict__ w5,
                            const float* __restrict__ w6,
                            unsigned short* __restrict__ ws) {
    int bid = blockIdx.x;
    int tid = threadIdx.x;
    if (bid >= 4096) {                 // weight blocks
        int tap = bid - 4096;
        const float* w = (tap == 0) ? w0 : (tap == 1) ? w1 : (tap == 2) ? w2
                       : (tap == 3) ? w3 : (tap == 4) ? w4 : (tap == 5) ? w5 : w6;
        unsigned p[8];
#pragma unroll
        for (int j = 0; j < 8; ++j)
            p[j] = pk2(w[tid * 16 + 2 * j], w[tid * 16 + 2 * j + 1]);
        uint4* dp = (uint4*)(ws + tap * 4096 + tid * 16);
        dp[0] = make_uint4(p[0], p[1], p[2], p[3]);
        dp[1] = make_uint4(p[4], p[5], p[6], p[7]);
        return;
    }
    int lbid = ((bid & 7) << 9) | (bid >> 3);   // bijective: 4096 % 8 == 0
    int b = lbid >> 9;                          // batch = XCD
    int i = (lbid & 511) * 256 + tid;           // [0, 131072) per batch
    int cg = i & 7;                             // channel group (8 ch)
    int s = (i >> 3) * 2;                       // even spatial row
    const float* xb = x + (size_t)b * CIN * SB;
    unsigned short* xq = ws + 7 * 4096;
    unsigned pa[4], pb[4];
#pragma unroll
    for (int u = 0; u < 4; ++u) {
        int ch = cg * 8 + 2 * u;
        float2 v0 = *(const float2*)(xb + (size_t)ch * SB + s);
        float2 v1 = *(const float2*)(xb + (size_t)(ch + 1) * SB + s);
        pa[u] = pk2(v0.x, v1.x);
        pb[u] = pk2(v0.y, v1.y);
    }
    uint4* dst = (uint4*)(xq + ((size_t)b * SB + s) * 64 + cg * 8);
    dst[0] = make_uint4(pa[0], pa[1], pa[2], pa[3]);   // row s
    dst[8] = make_uint4(pb[0], pb[1], pb[2], pb[3]);   // row s+1 (+128B)
}

// ---------------- pass 2: counted-vmcnt ring pipeline ----------------
// Block owns rc-slice [rc0, rc0+32) of batch b; iterates t = 0..31.
// Slab(t) = rows rc0-32..rc0+63 (clamped), 96 rows x 128 B = 12 KB,
// 16B chunks source-pre-swizzled (col ^ (row&7)); ring of 4 slabs (48 KB).
__global__ __launch_bounds__(512, 2) void conv10_kernel(const unsigned short* __restrict__ xq,
                                                        const unsigned short* __restrict__ wq,
                                                        float* __restrict__ out) {
    __shared__ uint4 ring[4][768];     // 48 KB
    int bid = blockIdx.x;
    int b = bid & 7;                   // batch = XCD (round-robin dispatch)
    int rc0 = (bid >> 3) << 5;         // rc-slice base, 0..992
    int tid = threadIdx.x;
    int lane = tid & 63;
    int wv = tid >> 6;                 // 0..7
    int lo = lane & 15;
    int quad = lane >> 4;
    int oq = wv & 3;                   // o-tile (16 outputs)
    int rh = wv >> 2;                  // row-half (16 rows)
    const uint4* xch = (const uint4*)(xq + (size_t)b * (CIN * SB));

    // ---- B preload: 14 frags (o-tile oq) -> 56 VGPRs, reused for all 32 t ----
    bf16x8 bq[7][2];
#pragma unroll
    for (int tap = 0; tap < 7; ++tap)
#pragma unroll
        for (int ks = 0; ks < 2; ++ks) {
            const unsigned short* bp = wq + tap * 4096
                + (oq * 16 + lo) * 64 + ks * 32 + quad * 8;
            bq[tap][ks] = __builtin_bit_cast(bf16x8, *(const s16x8*)bp);
        }

    // lane geometry (t-invariant)
    int rc = rc0 + rh * 16 + lo;       // output row's rc in [0,1024)
    int rl = 32 + rh * 16 + lo;        // local slab row in [32,64)
    int r = (rc >> 5) & 31;
    int c = rc & 31;
    bool okrm = (r > 0), okrp = (r < 31), okcm = (c > 0), okcp = (c < 31);

    // stage slab for t-slice ts into ring slot k: 768 chunks over 512 thr.
    // LDS dest linear (wave base + lane*16); source col pre-swizzled.
    auto stage = [&](int ts, int k) {
        {
            int cid = tid;                         // 0..511, rows 0..63
            int rw = cid >> 3;
            int sc = cid & 7;
            int rcx = rc0 - 32 + rw;
            rcx = rcx < 0 ? 0 : (rcx > 1023 ? 1023 : rcx);  // clamped rows feed masked lanes only
            const uint4* g = xch + ((size_t)(ts * 1024 + rcx) << 3) + (sc ^ (rw & 7));
            gload_lds16((const void*)g, (void*)(&ring[k][wv << 6]));
        }
        if (wv < 4) {                              // chunks 512..767, rows 64..95
            int cid = 512 + tid;
            int rw = cid >> 3;
            int sc = cid & 7;
            int rcx = rc0 - 32 + rw;
            rcx = rcx > 1023 ? 1023 : rcx;
            const uint4* g = xch + ((size_t)(ts * 1024 + rcx) << 3) + (sc ^ (rw & 7));
            gload_lds16((const void*)g, (void*)(&ring[k][512 + (wv << 6)]));
        }
    };

    const s16x8 zz = {0, 0, 0, 0, 0, 0, 0, 0};
    f32x4 acc_a, acc_b;                // dual chains (ks = 0 / 1)

    // one tap from LDS slab: 2 ds_read_b128 + 2 MFMA on independent chains
    auto tap_lds = [&](const uint4* slab, const bf16x8 (&bt)[2], int d, bool ok) {
        int row = rl + d;                          // always in [0,96)
        s16x8 a0 = *((const s16x8*)slab + row * 8 + ((quad) ^ (row & 7)));
        s16x8 a1 = *((const s16x8*)slab + row * 8 + ((4 + quad) ^ (row & 7)));
        a0 = ok ? a0 : zz;
        a1 = ok ? a1 : zz;
        acc_a = __builtin_amdgcn_mfma_f32_16x16x32_bf16(__builtin_bit_cast(bf16x8, a0), bt[0], acc_a, 0, 0, 0);
        acc_b = __builtin_amdgcn_mfma_f32_16x16x32_bf16(__builtin_bit_cast(bf16x8, a1), bt[1], acc_b, 0, 0, 0);
    };

    // ---- prologue: slabs for t=0,1 ----
    stage(0, 0);
    stage(1, 1);
    asm volatile("s_waitcnt vmcnt(0)" ::: "memory");
    __builtin_amdgcn_s_barrier();

    for (int t = 0; t < 32; ++t) {
        // counted wait: drains stage(t+1) (issued one full iter ago);
        // store(t-1) stays in flight -> no per-iter HBM-store drain.
        asm volatile("s_waitcnt vmcnt(1)" ::: "memory");
        __builtin_amdgcn_s_barrier();
        __builtin_amdgcn_sched_barrier(0);

        if (t + 2 < 32) stage(t + 2, (t + 2) & 3);   // slot (t+2)&3 not read this iter

        acc_a = (f32x4){0.f, 0.f, 0.f, 0.f};
        acc_b = (f32x4){0.f, 0.f, 0.f, 0.f};
        const uint4* sc_ = &ring[t & 3][0];

        tap_lds(sc_, bq[0], 0, true);                          // self
        if (t > 0)  tap_lds(&ring[(t - 1) & 3][0], bq[1], 0, true);   // t-1
        if (t < 31) tap_lds(&ring[(t + 1) & 3][0], bq[2], 0, true);   // t+1
        tap_lds(sc_, bq[3], -32, okrm);                        // r-1
        tap_lds(sc_, bq[4], 32, okrp);                         // r+1
        tap_lds(sc_, bq[5], -1, okcm);                         // c-1
        tap_lds(sc_, bq[6], 1, okcp);                          // c+1

        // D layout: col(o) = lane&15, row = quad*4 + reg
        size_t ob = ((size_t)(b * COUT + oq * 16 + lo)) * SB
                  + (size_t)t * 1024 + rc0 + rh * 16 + quad * 4;
        *(f32x4*)(out + ob) = acc_a + acc_b;
    }
}

// ---------------- tier-2 fallback: weights only ----------------
__global__ __launch_bounds__(256) void wprep_kernel(const float* __restrict__ w0,
                            const float* __restrict__ w1, const float* __restrict__ w2,
                            const float* __restrict__ w3, const float* __restrict__ w4,
                            const float* __restrict__ w5, const float* __restrict__ w6,
                            unsigned short* __restrict__ ws) {
    int tap = blockIdx.x;
    int tid = threadIdx.x;
    const float* w = (tap == 0) ? w0 : (tap == 1) ? w1 : (tap == 2) ? w2
                   : (tap == 3) ? w3 : (tap == 4) ? w4 : (tap == 5) ? w5 : w6;
    unsigned p[8];
#pragma unroll
    for (int j = 0; j < 8; ++j)
        p[j] = pk2(w[tid * 16 + 2 * j], w[tid * 16 + 2 * j + 1]);
    uint4* dp = (uint4*)(ws + tap * 4096 + tid * 16);
    dp[0] = make_uint4(p[0], p[1], p[2], p[3]);
    dp[1] = make_uint4(p[4], p[5], p[6], p[7]);
}

// ---------------- tier-2 fallback: fused LDS kernel on fp32 x ----------------
__global__ __launch_bounds__(256) void conv_kernel(const float* __restrict__ x,
                                                   const unsigned short* __restrict__ wq,
                                                   float* __restrict__ out) {
    __shared__ uint4 alds[2560];
    int bid = blockIdx.x;
    int b = bid >> 7;
    int sblk = (bid & 127) << 8;
    int tid = threadIdx.x;
    const float* xb = x + (size_t)b * CIN * SB;

    {
        int rl = 32 + tid;
        const float* xp = xb + sblk + tid;
#pragma unroll
        for (int c = 0; c < 4; ++c) {
            unsigned pk[8];
#pragma unroll
            for (int u = 0; u < 8; ++u)
                pk[u] = pk2(xp[(size_t)(c * 16 + 2 * u) * SB],
                            xp[(size_t)(c * 16 + 2 * u + 1) * SB]);
            alds[rl * 8 + ((2 * c) ^ (rl & 7))] = make_uint4(pk[0], pk[1], pk[2], pk[3]);
            alds[rl * 8 + ((2 * c + 1) ^ (rl & 7))] = make_uint4(pk[4], pk[5], pk[6], pk[7]);
        }
    }
    {
        int hrow = tid & 63;
        int rl = (hrow < 32) ? hrow : hrow + 256;
        int s = sblk - 32 + rl;
        s = max(0, min(SB - 1, s));
        int ic = tid >> 6;
        const float* xp = xb + s + (size_t)(ic * 16) * SB;
        unsigned pk[8];
#pragma unroll
        for (int u = 0; u < 8; ++u)
            pk[u] = pk2(xp[(size_t)(2 * u) * SB], xp[(size_t)(2 * u + 1) * SB]);
        alds[rl * 8 + ((2 * ic) ^ (rl & 7))] = make_uint4(pk[0], pk[1], pk[2], pk[3]);
        alds[rl * 8 + ((2 * ic + 1) ^ (rl & 7))] = make_uint4(pk[4], pk[5], pk[6], pk[7]);
    }
    __syncthreads();

    int lane = tid & 63;
    int wv = tid >> 6;
    int lo = lane & 15;
    int quad = lane >> 4;
    int sbase = sblk + wv * 64;
    int t = sblk >> 10;

    f32x4 acc[4][4];
#pragma unroll
    for (int mt = 0; mt < 4; ++mt)
#pragma unroll
        for (int nt = 0; nt < 4; ++nt)
            acc[mt][nt] = (f32x4){0.f, 0.f, 0.f, 0.f};

    int r_m[4], c_m[4], rl[4];
#pragma unroll
    for (int mt = 0; mt < 4; ++mt) {
        int s = sbase + mt * 16 + lo;
        r_m[mt] = (s >> 5) & 31;
        c_m[mt] = s & 31;
        rl[mt] = s - sblk + 32;
    }

    auto load_b = [&](const unsigned short* wt, int ks, int nt) -> bf16x8 {
        const unsigned short* bp = wt + (nt * 16 + lo) * 64 + ks * 32 + quad * 8;
        return __builtin_bit_cast(bf16x8, *(const s16x8*)bp);
    };

    auto run_tap_lds = [&](int tap, int d, const bool ok[4]) {
        const unsigned short* wt = wq + tap * 4096;
#pragma unroll
        for (int ks = 0; ks < 2; ++ks) {
            bf16x8 bf[4];
#pragma unroll
            for (int nt = 0; nt < 4; ++nt) bf[nt] = load_b(wt, ks, nt);
            int j = ks * 4 + quad;
#pragma unroll
            for (int mt = 0; mt < 4; ++mt) {
                int row = rl[mt] + d;
                s16x8 raw = *((const s16x8*)alds + row * 8 + (j ^ (row & 7)));
                s16x8 zx = {0, 0, 0, 0, 0, 0, 0, 0};
                raw = ok[mt] ? raw : zx;
                bf16x8 af = __builtin_bit_cast(bf16x8, raw);
#pragma unroll
                for (int nt = 0; nt < 4; ++nt)
                    acc[mt][nt] = __builtin_amdgcn_mfma_f32_16x16x32_bf16(af, bf[nt], acc[mt][nt], 0, 0, 0);
            }
        }
    };

    auto run_tap_gather = [&](int tap, int d) {
        const unsigned short* wt = wq + tap * 4096;
#pragma unroll
        for (int ks = 0; ks < 2; ++ks) {
            bf16x8 bf[4];
#pragma unroll
            for (int nt = 0; nt < 4; ++nt) bf[nt] = load_b(wt, ks, nt);
            const float* gp = xb + (size_t)(ks * 32 + quad * 8) * SB + d;
#pragma unroll
            for (int mt = 0; mt < 4; ++mt) {
                const float* ap = gp + sbase + mt * 16 + lo;
                unsigned pk[4];
#pragma unroll
                for (int u = 0; u < 4; ++u)
                    pk[u] = pk2(ap[(size_t)(2 * u) * SB], ap[(size_t)(2 * u + 1) * SB]);
                uint4 v = make_uint4(pk[0], pk[1], pk[2], pk[3]);
                bf16x8 af = __builtin_bit_cast(bf16x8, v);
#pragma unroll
                for (int nt = 0; nt < 4; ++nt)
                    acc[mt][nt] = __builtin_amdgcn_mfma_f32_16x16x32_bf16(af, bf[nt], acc[mt][nt], 0, 0, 0);
            }
        }
    };

    {
        bool ok_all[4] = {true, true, true, true};
        run_tap_lds(0, 0, ok_all);
    }
    if (t > 0)  run_tap_gather(1, -1024);
    if (t < 31) run_tap_gather(2, 1024);
    {
        bool ok[4];
#pragma unroll
        for (int mt = 0; mt < 4; ++mt) ok[mt] = (r_m[mt] > 0);
        run_tap_lds(3, -32, ok);
#pragma unroll
        for (int mt = 0; mt < 4; ++mt) ok[mt] = (r_m[mt] < 31);
        run_tap_lds(4, 32, ok);
#pragma unroll
        for (int mt = 0; mt < 4; ++mt) ok[mt] = (c_m[mt] > 0);
        run_tap_lds(5, -1, ok);
#pragma unroll
        for (int mt = 0; mt < 4; ++mt) ok[mt] = (c_m[mt] < 31);
        run_tap_lds(6, 1, ok);
    }

#pragma unroll
    for (int mt = 0; mt < 4; ++mt) {
#pragma unroll
        for (int nt = 0; nt < 4; ++nt) {
            int o = nt * 16 + lo;
            size_t off = ((size_t)(b * COUT + o)) * SB + sbase + mt * 16 + quad * 4;
            *(f32x4*)(out + off) = acc[mt][nt];
        }
    }
}

// ---------------- tier-3 fallback: fp32 direct ----------------
__global__ void fallback_kernel(const float* __restrict__ x,
                                const float* __restrict__ w0, const float* __restrict__ w1,
                                const float* __restrict__ w2, const float* __restrict__ w3,
                                const float* __restrict__ w4, const float* __restrict__ w5,
                                const float* __restrict__ w6,
                                float* __restrict__ out) {
    int bid = blockIdx.x;
    int b = bid >> 11;
    int og = (bid >> 7) & 15;
    int sblk = (bid & 127) << 8;
    int tid = threadIdx.x;
    __shared__ float wl[7][4][64];
    const float* wp[7] = {w0, w1, w2, w3, w4, w5, w6};
    for (int k = tid; k < 7 * 4 * 64; k += 256) {
        int tap = k >> 8, oo = (k >> 6) & 3, i = k & 63;
        wl[tap][oo][i] = wp[tap][(og * 4 + oo) * 64 + i];
    }
    __syncthreads();
    int s = sblk + tid;
    int t = s >> 10, r = (s >> 5) & 31, c = s & 31;
    const float* xb = x + (size_t)b * CIN * SB + s;
    float a0 = 0, a1 = 0, a2 = 0, a3 = 0;
    for (int i = 0; i < 64; ++i) {
        const float* xi = xb + (size_t)i * SB;
        float vs = xi[0];
        float vtp = (t > 0) ? xi[-1024] : 0.f;
        float vtm = (t < 31) ? xi[1024] : 0.f;
        float vrp = (r > 0) ? xi[-32] : 0.f;
        float vrm = (r < 31) ? xi[32] : 0.f;
        float vcp = (c > 0) ? xi[-1] : 0.f;
        float vcm = (c < 31) ? xi[1] : 0.f;
        a0 += wl[0][0][i] * vs + wl[1][0][i] * vtp + wl[2][0][i] * vtm + wl[3][0][i] * vrp + wl[4][0][i] * vrm + wl[5][0][i] * vcp + wl[6][0][i] * vcm;
        a1 += wl[0][1][i] * vs + wl[1][1][i] * vtp + wl[2][1][i] * vtm + wl[3][1][i] * vrp + wl[4][1][i] * vrm + wl[5][1][i] * vcp + wl[6][1][i] * vcm;
        a2 += wl[0][2][i] * vs + wl[1][2][i] * vtp + wl[2][2][i] * vtm + wl[3][2][i] * vrp + wl[4][2][i] * vrm + wl[5][2][i] * vcp + wl[6][2][i] * vcm;
        a3 += wl[0][3][i] * vs + wl[1][3][i] * vtp + wl[2][3][i] * vtm + wl[3][3][i] * vrp + wl[4][3][i] * vrm + wl[5][3][i] * vcp + wl[6][3][i] * vcm;
    }
    size_t obase = ((size_t)b * COUT + og * 4) * SB + s;
    out[obase] = a0;
    out[obase + SB] = a1;
    out[obase + 2 * (size_t)SB] = a2;
    out[obase + 3 * (size_t)SB] = a3;
}

extern "C" void kernel_launch(void* const* d_in, const int* in_sizes, int n_in,
                              void* d_out, int out_size, void* d_ws, size_t ws_size,
                              hipStream_t stream) {
    const float* x = (const float*)d_in[0];
    const float* w0 = (const float*)d_in[1];
    const float* w1 = (const float*)d_in[2];
    const float* w2 = (const float*)d_in[3];
    const float* w3 = (const float*)d_in[4];
    const float* w4 = (const float*)d_in[5];
    const float* w5 = (const float*)d_in[6];
    const float* w6 = (const float*)d_in[7];
    float* out = (float*)d_out;

    size_t need_w = (size_t)7 * 4096 * 2;                        // 56 KB weights
    size_t need_full = need_w + (size_t)NB * CIN * SB * 2;       // + 32 MB bf16 x
    if (d_ws != nullptr && ws_size >= need_full) {
        unsigned short* wsp = (unsigned short*)d_ws;
        prep2_kernel<<<4103, 256, 0, stream>>>(x, w0, w1, w2, w3, w4, w5, w6, wsp);
        conv10_kernel<<<256, 512, 0, stream>>>(wsp + 7 * 4096, wsp, out);
    } else if (d_ws != nullptr && ws_size >= need_w) {
        unsigned short* wsp = (unsigned short*)d_ws;
        wprep_kernel<<<7, 256, 0, stream>>>(w0, w1, w2, w3, w4, w5, w6, wsp);
        conv_kernel<<<1024, 256, 0, stream>>>(x, wsp, out);
    } else {
        fallback_kernel<<<8 * 16 * 128, 256, 0, stream>>>(x, w0, w1, w2, w3, w4, w5, w6, out);
    }
}